// Round 1
// baseline (2803.334 us; speedup 1.0000x reference)
//
#include <hip/hip_runtime.h>
#include <hip/hip_bf16.h>

// ---------------- problem constants ----------------
namespace {
constexpr int Bb = 128, Nn = 12800, Ee = 262144;
constexpr int LAT = 256, HID = 128, FCH = 512, NRBF = 16;
constexpr int TE = 16; // edges per block in edge kernel

// workspace offsets (floats)
constexpr int WS_L      = 0;        // B*9
constexpr int WS_LI     = 1152;     // B*9
constexpr int WS_SIG    = 2304;     // B
constexpr int WS_RBFW2  = 2432;     // 16*128
constexpr int WS_CVEC   = 4480;     // 128
constexpr int WS_HB     = 4608;     // 100*128
constexpr int WS_LATP   = 17408;    // B*512
constexpr int WS_PERT   = 82944;    // N*3
constexpr int WS_ALIGN  = 121344;   // N*3
constexpr int WS_SN     = 159744;   // N*3 (atomic)
constexpr int WS_GN     = 198144;   // N*3 (atomic)
constexpr int WS_PREDS  = 236544;   // N*3
constexpr int WS_BSUM   = 274944;   // B*3 (atomic)
constexpr int WS_CENTER = 275328;   // B*3 (atomic)
constexpr int WS_MINMAX = 275712;   // 6   (max x3, min x3)
}

static __device__ __forceinline__ void atomicMaxFloat(float* addr, float val) {
  int* ai = reinterpret_cast<int*>(addr);
  int old = *ai;
  while (__int_as_float(old) < val) {
    int assumed = old;
    old = atomicCAS(ai, assumed, __float_as_int(val));
    if (old == assumed) break;
  }
}
static __device__ __forceinline__ void atomicMinFloat(float* addr, float val) {
  int* ai = reinterpret_cast<int*>(addr);
  int old = *ai;
  while (__int_as_float(old) > val) {
    int assumed = old;
    old = atomicCAS(ai, assumed, __float_as_int(val));
    if (old == assumed) break;
  }
}

// ---------------- init: zero accumulators, init minmax ----------------
__global__ void k_init(float* ws) {
  int i = blockIdx.x * blockDim.x + threadIdx.x;
  int stride = gridDim.x * blockDim.x;
  for (int k = i; k < 2 * Nn * 3; k += stride) ws[WS_SN + k] = 0.f;     // sN, gN
  for (int k = i; k < 2 * Bb * 3; k += stride) ws[WS_BSUM + k] = 0.f;   // bsum, center
  if (i < 3) ws[WS_MINMAX + i] = -3.0e38f;
  else if (i < 6) ws[WS_MINMAX + i] = 3.0e38f;
}

// ---------------- lattice, inverse, sigma per batch ----------------
__global__ void k_lattice(const float* lengths, const float* angles,
                          const float* sigmas, const int* tsteps, float* ws) {
  int b = threadIdx.x;
  if (b >= Bb) return;
  float a = lengths[b * 3 + 0], bl = lengths[b * 3 + 1], c = lengths[b * 3 + 2];
  const float d2r = 0.017453292519943295f;
  float al = angles[b * 3 + 0] * d2r, be = angles[b * 3 + 1] * d2r, ga = angles[b * 3 + 2] * d2r;
  float ca = cosf(al), cb = cosf(be), cg = cosf(ga), sa = sinf(al), sb = sinf(be);
  float val = (ca * cb - cg) / (sa * sb);
  val = fminf(1.f, fmaxf(-1.f, val));
  float gs = acosf(val);
  float L[3][3];
  L[0][0] = a * sb;              L[0][1] = 0.f;                L[0][2] = a * cb;
  L[1][0] = -bl * sa * cosf(gs); L[1][1] = bl * sa * sinf(gs); L[1][2] = bl * ca;
  L[2][0] = 0.f;                 L[2][1] = 0.f;                L[2][2] = c;
  float c00 = L[1][1] * L[2][2] - L[1][2] * L[2][1];
  float c01 = -(L[1][0] * L[2][2] - L[1][2] * L[2][0]);
  float c02 = L[1][0] * L[2][1] - L[1][1] * L[2][0];
  float det = L[0][0] * c00 + L[0][1] * c01 + L[0][2] * c02;
  float id = 1.f / det;
  float inv[3][3];
  inv[0][0] =  (L[1][1]*L[2][2] - L[1][2]*L[2][1]) * id;
  inv[0][1] = -(L[0][1]*L[2][2] - L[0][2]*L[2][1]) * id;
  inv[0][2] =  (L[0][1]*L[1][2] - L[0][2]*L[1][1]) * id;
  inv[1][0] = -(L[1][0]*L[2][2] - L[1][2]*L[2][0]) * id;
  inv[1][1] =  (L[0][0]*L[2][2] - L[0][2]*L[2][0]) * id;
  inv[1][2] = -(L[0][0]*L[1][2] - L[0][2]*L[1][0]) * id;
  inv[2][0] =  (L[1][0]*L[2][1] - L[1][1]*L[2][0]) * id;
  inv[2][1] = -(L[0][0]*L[2][1] - L[0][1]*L[2][0]) * id;
  inv[2][2] =  (L[0][0]*L[1][1] - L[0][1]*L[1][0]) * id;
  for (int i = 0; i < 3; ++i)
    for (int j = 0; j < 3; ++j) {
      ws[WS_L + b * 9 + i * 3 + j] = L[i][j];
      ws[WS_LI + b * 9 + i * 3 + j] = inv[i][j];
    }
  ws[WS_SIG + b] = sigmas[tsteps[b]];
}

// ---------------- hb = atom_emb @ bb_W ----------------
__global__ void k_hb(const float* aemb, const float* bbW, float* ws) {
  int t = blockIdx.x, c = threadIdx.x;
  float acc = 0.f;
  for (int k = 0; k < HID; ++k) acc += aemb[t * HID + k] * bbW[k * HID + c];
  ws[WS_HB + t * HID + c] = acc;
}

// ---------------- rbfW2 = rbf_W @ bb_W ; cvec = rbf_b @ bb_W + bb_b ----------------
__global__ void k_rbfw2(const float* rbfW, const float* rbfb,
                        const float* bbW, const float* bbb, float* ws) {
  int c = threadIdx.x;
  float accs[NRBF];
#pragma unroll
  for (int k = 0; k < NRBF; ++k) accs[k] = 0.f;
  float accb = 0.f;
  for (int m = 0; m < HID; ++m) {
    float w = bbW[m * HID + c];
#pragma unroll
    for (int k = 0; k < NRBF; ++k) accs[k] += rbfW[k * HID + m] * w;
    accb += rbfb[m] * w;
  }
#pragma unroll
  for (int k = 0; k < NRBF; ++k) ws[WS_RBFW2 + k * HID + c] = accs[k];
  ws[WS_CVEC + c] = accb + bbb[c];
}

// ---------------- lat_proj = latents @ sc_W0[128:384] + b0 ----------------
__global__ void k_latproj(const float* latents, const float* scW0,
                          const float* scb0, float* ws) {
  int b = blockIdx.x, t = threadIdx.x;
  __shared__ float lat[LAT];
  lat[t] = latents[b * LAT + t];
  __syncthreads();
  int c0 = 2 * t;
  float a0 = 0.f, a1 = 0.f;
  for (int m = 0; m < LAT; ++m) {
    float2 w = *reinterpret_cast<const float2*>(scW0 + (HID + m) * FCH + c0);
    float lm = lat[m];
    a0 += lm * w.x;
    a1 += lm * w.y;
  }
  ws[WS_LATP + b * FCH + c0] = a0 + scb0[c0];
  ws[WS_LATP + b * FCH + c0 + 1] = a1 + scb0[c0 + 1];
}

// ---------------- per-node geometry ----------------
__global__ void k_node(const float* frac, const float* noise, const int* batch, float* ws) {
  int n = blockIdx.x * blockDim.x + threadIdx.x;
  if (n >= Nn) return;
  int b = batch[n];
  float L[9], Li[9];
#pragma unroll
  for (int i = 0; i < 9; ++i) { L[i] = ws[WS_L + b * 9 + i]; Li[i] = ws[WS_LI + b * 9 + i]; }
  float f0 = frac[n * 3], f1 = frac[n * 3 + 1], f2 = frac[n * 3 + 2];
  float cg[3], p0[3], fp[3], pe[3], fg[3], fd[3];
#pragma unroll
  for (int j = 0; j < 3; ++j) cg[j] = f0 * L[j] + f1 * L[3 + j] + f2 * L[6 + j];
  float sig = ws[WS_SIG + b];
#pragma unroll
  for (int j = 0; j < 3; ++j) p0[j] = cg[j] + sig * noise[n * 3 + j];
#pragma unroll
  for (int j = 0; j < 3; ++j) {
    float v = p0[0] * Li[j] + p0[1] * Li[3 + j] + p0[2] * Li[6 + j];
    fp[j] = v - floorf(v);
  }
#pragma unroll
  for (int j = 0; j < 3; ++j) pe[j] = fp[0] * L[j] + fp[1] * L[3 + j] + fp[2] * L[6 + j];
#pragma unroll
  for (int j = 0; j < 3; ++j) fg[j] = cg[0] * Li[j] + cg[1] * Li[3 + j] + cg[2] * Li[6 + j];
#pragma unroll
  for (int j = 0; j < 3; ++j) { float d = fg[j] - fp[j]; fd[j] = d - rintf(d); }
#pragma unroll
  for (int j = 0; j < 3; ++j) {
    ws[WS_PERT + n * 3 + j] = pe[j];
    ws[WS_ALIGN + n * 3 + j] = pe[j] + fd[0] * L[j] + fd[1] * L[3 + j] + fd[2] * L[6 + j];
  }
}

// ---------------- the big fused edge kernel ----------------
__global__ __launch_bounds__(256, 3) void k_edge(
    const int* ei, const int* toj, const int* batch, const int* atype,
    const float* scW0, const float* scW1, const float* scb1,
    const float* scW2, const float* scb2, float* ws) {
  __shared__ __align__(16) float s_efT[HID][TE];   // 8 KB  (ef transposed)
  __shared__ __align__(16) float s_hhT[FCH][TE];   // 32 KB (hh0 transposed)
  __shared__ float s_dvec[TE][3];
  __shared__ float s_dist[TE], s_gtd[TE];
  __shared__ float s_rbf[TE][NRBF];
  __shared__ int s_b[TE], s_iN[TE], s_tj[TE], s_ti[TE];
  __shared__ float s_wsum[4][TE];

  const int t = threadIdx.x;
  const int e0 = blockIdx.x * TE;

  // Phase A: per-edge geometry + rbf (threads 0..15)
  if (t < TE) {
    int e = e0 + t;
    int jn = ei[e], iN = ei[Ee + e];
    int b = batch[jn];
    float tx = (float)toj[e * 3], ty = (float)toj[e * 3 + 1], tz = (float)toj[e * 3 + 2];
    const float* L = ws + WS_L + b * 9;
    float dv[3], gv[3];
#pragma unroll
    for (int j = 0; j < 3; ++j) {
      float off = tx * L[j] + ty * L[3 + j] + tz * L[6 + j];
      dv[j] = ws[WS_PERT + iN * 3 + j] - ws[WS_PERT + jn * 3 + j] - off;
      gv[j] = ws[WS_ALIGN + iN * 3 + j] - ws[WS_ALIGN + jn * 3 + j] - off;
    }
    float dist = sqrtf(dv[0] * dv[0] + dv[1] * dv[1] + dv[2] * dv[2]);
    float gtd = sqrtf(gv[0] * gv[0] + gv[1] * gv[1] + gv[2] * gv[2]);
#pragma unroll
    for (int j = 0; j < 3; ++j) s_dvec[t][j] = dv[j];
    s_dist[t] = dist;
    s_gtd[t] = gtd;
    s_b[t] = b; s_iN[t] = iN; s_tj[t] = atype[jn]; s_ti[t] = atype[iN];
    const float step = 7.0f / 15.0f;
#pragma unroll
    for (int k = 0; k < NRBF; ++k) {
      float d = dist - (float)k * step;
      s_rbf[t][k] = expf(-10.f * d * d);
    }
  }
  __syncthreads();

  // Phase B: ef = silu(hb[tj]+hb[ti]+rbf@rbfW2+cvec), transposed into LDS
  {
    int e = t >> 4, sub = t & 15;
    int tj = s_tj[e], ti = s_ti[e];
    float rb[NRBF];
#pragma unroll
    for (int k = 0; k < NRBF; ++k) rb[k] = s_rbf[e][k];
#pragma unroll
    for (int cc = 0; cc < 8; ++cc) {
      int c = sub * 8 + cc;
      float z = ws[WS_HB + tj * HID + c] + ws[WS_HB + ti * HID + c] + ws[WS_CVEC + c];
#pragma unroll
      for (int k = 0; k < NRBF; ++k) z += rb[k] * ws[WS_RBFW2 + k * HID + c];
      s_efT[c][e] = z / (1.f + expf(-z));
    }
  }
  __syncthreads();

  const int cg = t >> 2;
  const int c = cg * 8;
  const int eg4 = (t & 3) * 4;

  // Phase C: GEMM1  hh0 = relu(ef @ W0a + lat_proj[b])
  {
    float acc[4][8];
#pragma unroll
    for (int j = 0; j < 4; ++j)
#pragma unroll
      for (int cc = 0; cc < 8; ++cc) acc[j][cc] = 0.f;
#pragma unroll 2
    for (int k = 0; k < HID; ++k) {
      const float4 xv = *reinterpret_cast<const float4*>(&s_efT[k][eg4]);
      const float4 wa = *reinterpret_cast<const float4*>(scW0 + k * FCH + c);
      const float4 wb = *reinterpret_cast<const float4*>(scW0 + k * FCH + c + 4);
      const float x[4] = {xv.x, xv.y, xv.z, xv.w};
      const float w[8] = {wa.x, wa.y, wa.z, wa.w, wb.x, wb.y, wb.z, wb.w};
#pragma unroll
      for (int j = 0; j < 4; ++j)
#pragma unroll
        for (int cc = 0; cc < 8; ++cc) acc[j][cc] += x[j] * w[cc];
    }
#pragma unroll
    for (int j = 0; j < 4; ++j) {
      int b = s_b[eg4 + j];
#pragma unroll
      for (int cc = 0; cc < 8; ++cc) {
        float h = acc[j][cc] + ws[WS_LATP + b * FCH + c + cc];
        s_hhT[c + cc][eg4 + j] = fmaxf(h, 0.f);
      }
    }
  }
  __syncthreads();

  // Phase D: GEMM2  hh1 = relu(hh0 @ W1 + b1); partial score = hh1 . W2
  {
    float acc[4][8];
#pragma unroll
    for (int j = 0; j < 4; ++j)
#pragma unroll
      for (int cc = 0; cc < 8; ++cc) acc[j][cc] = 0.f;
#pragma unroll 2
    for (int k = 0; k < FCH; ++k) {
      const float4 xv = *reinterpret_cast<const float4*>(&s_hhT[k][eg4]);
      const float4 wa = *reinterpret_cast<const float4*>(scW1 + k * FCH + c);
      const float4 wb = *reinterpret_cast<const float4*>(scW1 + k * FCH + c + 4);
      const float x[4] = {xv.x, xv.y, xv.z, xv.w};
      const float w[8] = {wa.x, wa.y, wa.z, wa.w, wb.x, wb.y, wb.z, wb.w};
#pragma unroll
      for (int j = 0; j < 4; ++j)
#pragma unroll
        for (int cc = 0; cc < 8; ++cc) acc[j][cc] += x[j] * w[cc];
    }
    float p[4] = {0.f, 0.f, 0.f, 0.f};
#pragma unroll
    for (int cc = 0; cc < 8; ++cc) {
      float b1v = scb1[c + cc];
      float w2v = scW2[c + cc];
#pragma unroll
      for (int j = 0; j < 4; ++j) {
        float h = fmaxf(acc[j][cc] + b1v, 0.f);
        p[j] += h * w2v;
      }
    }
    // reduce across the 16 col-groups of each wave (lane bits 2..5)
#pragma unroll
    for (int j = 0; j < 4; ++j) {
      float v = p[j];
      v += __shfl_xor(v, 4);
      v += __shfl_xor(v, 8);
      v += __shfl_xor(v, 16);
      v += __shfl_xor(v, 32);
      p[j] = v;
    }
    if ((t & 63) < 4) {
      int eg = t & 3;
#pragma unroll
      for (int j = 0; j < 4; ++j) s_wsum[t >> 6][eg * 4 + j] = p[j];
    }
  }
  __syncthreads();

  // Phase E: scatter with segment-mean weights (threads 0..15)
  if (t < TE) {
    int e = e0 + t;
    float score = scb2[0] + s_wsum[0][t] + s_wsum[1][t] + s_wsum[2][t] + s_wsum[3][t];
    int jn = ei[e], iN = ei[Ee + e];
    int s = e;
    while (s > 0 && ei[s - 1] == jn && ei[Ee + s - 1] == iN) --s;
    int en = e;
    while (en + 1 < Ee && ei[en + 1] == jn && ei[Ee + en + 1] == iN) ++en;
    float invc = 1.f / (float)(en - s + 1);
    float dist = s_dist[t];
    float denom = dist + 1e-8f;
    float gts = s_gtd[t] - dist;
#pragma unroll
    for (int j = 0; j < 3; ++j) {
      float dir = s_dvec[t][j] / denom;
      atomicAdd(&ws[WS_SN + iN * 3 + j], score * dir * invc);
      atomicAdd(&ws[WS_GN + iN * 3 + j], gts * dir * invc);
    }
  }
}

// ---------------- per-node: loss terms, preds, center sums ----------------
__global__ void k_node2(const int* batch, float* ws) {
  int n = blockIdx.x * blockDim.x + threadIdx.x;
  if (n >= Nn) return;
  int b = batch[n];
  float sig = ws[WS_SIG + b];
#pragma unroll
  for (int j = 0; j < 3; ++j) {
    float s = ws[WS_SN + n * 3 + j], g = ws[WS_GN + n * 3 + j];
    float d = s - g / sig;
    atomicAdd(&ws[WS_BSUM + b * 3 + j], d * d);
    float pr = ws[WS_PERT + n * 3 + j] + s / sig;
    ws[WS_PREDS + n * 3 + j] = pr;
    atomicAdd(&ws[WS_CENTER + b * 3 + j], pr);
  }
}

// ---------------- per-node: global min/max of dc ----------------
__global__ void k_minmax(const int* batch, const int* num_atoms, float* ws) {
  int n = blockIdx.x * blockDim.x + threadIdx.x;
  int lane = threadIdx.x & 63, wid = threadIdx.x >> 6;
  float mx[3], mn[3];
  if (n < Nn) {
    int b = batch[n];
    float na = (float)num_atoms[b];
#pragma unroll
    for (int j = 0; j < 3; ++j) {
      float v = ws[WS_PREDS + n * 3 + j] - ws[WS_CENTER + b * 3 + j] / na;
      mx[j] = v; mn[j] = v;
    }
  } else {
#pragma unroll
    for (int j = 0; j < 3; ++j) { mx[j] = -3.0e38f; mn[j] = 3.0e38f; }
  }
#pragma unroll
  for (int off = 32; off >= 1; off >>= 1) {
#pragma unroll
    for (int j = 0; j < 3; ++j) {
      mx[j] = fmaxf(mx[j], __shfl_xor(mx[j], off));
      mn[j] = fminf(mn[j], __shfl_xor(mn[j], off));
    }
  }
  __shared__ float smx[4][3], smn[4][3];
  if (lane == 0) {
#pragma unroll
    for (int j = 0; j < 3; ++j) { smx[wid][j] = mx[j]; smn[wid][j] = mn[j]; }
  }
  __syncthreads();
  if (threadIdx.x == 0) {
#pragma unroll
    for (int j = 0; j < 3; ++j) {
      float M = fmaxf(fmaxf(smx[0][j], smx[1][j]), fmaxf(smx[2][j], smx[3][j]));
      float m = fminf(fminf(smn[0][j], smn[1][j]), fminf(smn[2][j], smn[3][j]));
      atomicMaxFloat(&ws[WS_MINMAX + j], M);
      atomicMinFloat(&ws[WS_MINMAX + 3 + j], m);
    }
  }
}

// ---------------- finalize ----------------
__global__ void k_final(const int* num_atoms, const float* ws, float* out) {
  float loss = 0.f;
  for (int b = 0; b < Bb; ++b) {
    float na = (float)num_atoms[b];
    for (int j = 0; j < 3; ++j) loss += ws[WS_BSUM + b * 3 + j] / na;
  }
  loss /= (3.0f * (float)Bb);
  float pbs = fabsf(ws[WS_MINMAX + 0] + ws[WS_MINMAX + 3]) +
              fabsf(ws[WS_MINMAX + 1] + ws[WS_MINMAX + 4]) +
              fabsf(ws[WS_MINMAX + 2] + ws[WS_MINMAX + 5]);
  out[0] = loss;
  out[1] = pbs;
}

extern "C" void kernel_launch(void* const* d_in, const int* in_sizes, int n_in,
                              void* d_out, int out_size, void* d_ws, size_t ws_size,
                              hipStream_t stream) {
  const float* latents = (const float*)d_in[0];
  const float* gtf     = (const float*)d_in[1];
  const float* lengths = (const float*)d_in[2];
  const float* angles  = (const float*)d_in[3];
  const float* noise   = (const float*)d_in[4];
  const float* sigmas  = (const float*)d_in[5];
  const float* aemb    = (const float*)d_in[6];
  const float* rbfW    = (const float*)d_in[7];
  const float* rbfb    = (const float*)d_in[8];
  const float* bbW     = (const float*)d_in[9];
  const float* bbb     = (const float*)d_in[10];
  const float* scW0    = (const float*)d_in[11];
  const float* scb0    = (const float*)d_in[12];
  const float* scW1    = (const float*)d_in[13];
  const float* scb1    = (const float*)d_in[14];
  const float* scW2    = (const float*)d_in[15];
  const float* scb2    = (const float*)d_in[16];
  const int* num_atoms = (const int*)d_in[17];
  const int* atype     = (const int*)d_in[18];
  const int* batch     = (const int*)d_in[19];
  const int* ei        = (const int*)d_in[20];
  const int* toj       = (const int*)d_in[21];
  const int* tsteps    = (const int*)d_in[22];
  float* ws = (float*)d_ws;
  float* out = (float*)d_out;

  hipLaunchKernelGGL(k_init, dim3(256), dim3(256), 0, stream, ws);
  hipLaunchKernelGGL(k_lattice, dim3(1), dim3(128), 0, stream, lengths, angles, sigmas, tsteps, ws);
  hipLaunchKernelGGL(k_hb, dim3(100), dim3(128), 0, stream, aemb, bbW, ws);
  hipLaunchKernelGGL(k_rbfw2, dim3(1), dim3(128), 0, stream, rbfW, rbfb, bbW, bbb, ws);
  hipLaunchKernelGGL(k_latproj, dim3(128), dim3(256), 0, stream, latents, scW0, scb0, ws);
  hipLaunchKernelGGL(k_node, dim3(50), dim3(256), 0, stream, gtf, noise, batch, ws);
  hipLaunchKernelGGL(k_edge, dim3(Ee / TE), dim3(256), 0, stream,
                     ei, toj, batch, atype, scW0, scW1, scb1, scW2, scb2, ws);
  hipLaunchKernelGGL(k_node2, dim3(50), dim3(256), 0, stream, batch, ws);
  hipLaunchKernelGGL(k_minmax, dim3(50), dim3(256), 0, stream, batch, num_atoms, ws);
  hipLaunchKernelGGL(k_final, dim3(1), dim3(1), 0, stream, num_atoms, ws, out);
}

// Round 2
// 938.201 us; speedup vs baseline: 2.9880x; 2.9880x over previous
//
#include <hip/hip_runtime.h>
#include <hip/hip_bf16.h>

// ---------------- problem constants ----------------
namespace {
constexpr int Bb = 128, Nn = 12800, Ee = 262144;
constexpr int LAT = 256, HID = 128, FCH = 512, NRBF = 16;
constexpr int TE = 32; // edges per block in edge kernel (divides 2048 = edges/graph)

// workspace offsets (floats)
constexpr int WS_L      = 0;        // B*9
constexpr int WS_LI     = 1152;     // B*9
constexpr int WS_SIG    = 2304;     // B
constexpr int WS_RBFW2  = 2432;     // 16*128
constexpr int WS_CVEC   = 4480;     // 128
constexpr int WS_HB     = 4608;     // 100*128
constexpr int WS_LATP   = 17408;    // B*512
constexpr int WS_PERT   = 82944;    // N*3
constexpr int WS_ALIGN  = 121344;   // N*3
constexpr int WS_SN     = 159744;   // N*3 (atomic)
constexpr int WS_GN     = 198144;   // N*3 (atomic)
constexpr int WS_PREDS  = 236544;   // N*3
constexpr int WS_BSUM   = 274944;   // B*3 (atomic)
constexpr int WS_CENTER = 275328;   // B*3 (atomic)
constexpr int WS_MINMAX = 275712;   // 6   (max x3, min x3)
// bf16 transposed weights (stored as ushort), float-index base:
constexpr int WS_W0T_F  = 276000;   // ushort[512*128]  (= 32768 floats)
constexpr int WS_W1T_F  = 308768;   // ushort[512*512]  (= 131072 floats)
}

typedef short bf16x8 __attribute__((ext_vector_type(8)));
typedef unsigned short u16x8 __attribute__((ext_vector_type(8)));
typedef float f32x4 __attribute__((ext_vector_type(4)));

static __device__ __forceinline__ unsigned short f2bf(float f) {
  unsigned int u = __float_as_uint(f);
  unsigned int r = (u + 0x7fffu + ((u >> 16) & 1u)) >> 16;
  return (unsigned short)r;
}

static __device__ __forceinline__ void atomicMaxFloat(float* addr, float val) {
  int* ai = reinterpret_cast<int*>(addr);
  int old = *ai;
  while (__int_as_float(old) < val) {
    int assumed = old;
    old = atomicCAS(ai, assumed, __float_as_int(val));
    if (old == assumed) break;
  }
}
static __device__ __forceinline__ void atomicMinFloat(float* addr, float val) {
  int* ai = reinterpret_cast<int*>(addr);
  int old = *ai;
  while (__int_as_float(old) > val) {
    int assumed = old;
    old = atomicCAS(ai, assumed, __float_as_int(val));
    if (old == assumed) break;
  }
}

// ---------------- init: zero accumulators, init minmax ----------------
__global__ void k_init(float* ws) {
  int i = blockIdx.x * blockDim.x + threadIdx.x;
  int stride = gridDim.x * blockDim.x;
  for (int k = i; k < 2 * Nn * 3; k += stride) ws[WS_SN + k] = 0.f;
  for (int k = i; k < 2 * Bb * 3; k += stride) ws[WS_BSUM + k] = 0.f;
  if (i < 3) ws[WS_MINMAX + i] = -3.0e38f;
  else if (i < 6) ws[WS_MINMAX + i] = 3.0e38f;
}

// ---------------- lattice, inverse, sigma per batch ----------------
__global__ void k_lattice(const float* lengths, const float* angles,
                          const float* sigmas, const int* tsteps, float* ws) {
  int b = threadIdx.x;
  if (b >= Bb) return;
  float a = lengths[b * 3 + 0], bl = lengths[b * 3 + 1], c = lengths[b * 3 + 2];
  const float d2r = 0.017453292519943295f;
  float al = angles[b * 3 + 0] * d2r, be = angles[b * 3 + 1] * d2r, ga = angles[b * 3 + 2] * d2r;
  float ca = cosf(al), cb = cosf(be), cg = cosf(ga), sa = sinf(al), sb = sinf(be);
  float val = (ca * cb - cg) / (sa * sb);
  val = fminf(1.f, fmaxf(-1.f, val));
  float gs = acosf(val);
  float L[3][3];
  L[0][0] = a * sb;              L[0][1] = 0.f;                L[0][2] = a * cb;
  L[1][0] = -bl * sa * cosf(gs); L[1][1] = bl * sa * sinf(gs); L[1][2] = bl * ca;
  L[2][0] = 0.f;                 L[2][1] = 0.f;                L[2][2] = c;
  float c00 = L[1][1] * L[2][2] - L[1][2] * L[2][1];
  float c01 = -(L[1][0] * L[2][2] - L[1][2] * L[2][0]);
  float c02 = L[1][0] * L[2][1] - L[1][1] * L[2][0];
  float det = L[0][0] * c00 + L[0][1] * c01 + L[0][2] * c02;
  float id = 1.f / det;
  float inv[3][3];
  inv[0][0] =  (L[1][1]*L[2][2] - L[1][2]*L[2][1]) * id;
  inv[0][1] = -(L[0][1]*L[2][2] - L[0][2]*L[2][1]) * id;
  inv[0][2] =  (L[0][1]*L[1][2] - L[0][2]*L[1][1]) * id;
  inv[1][0] = -(L[1][0]*L[2][2] - L[1][2]*L[2][0]) * id;
  inv[1][1] =  (L[0][0]*L[2][2] - L[0][2]*L[2][0]) * id;
  inv[1][2] = -(L[0][0]*L[1][2] - L[0][2]*L[1][0]) * id;
  inv[2][0] =  (L[1][0]*L[2][1] - L[1][1]*L[2][0]) * id;
  inv[2][1] = -(L[0][0]*L[2][1] - L[0][1]*L[2][0]) * id;
  inv[2][2] =  (L[0][0]*L[1][1] - L[0][1]*L[1][0]) * id;
  for (int i = 0; i < 3; ++i)
    for (int j = 0; j < 3; ++j) {
      ws[WS_L + b * 9 + i * 3 + j] = L[i][j];
      ws[WS_LI + b * 9 + i * 3 + j] = inv[i][j];
    }
  ws[WS_SIG + b] = sigmas[tsteps[b]];
}

// ---------------- hb = atom_emb @ bb_W ----------------
__global__ void k_hb(const float* aemb, const float* bbW, float* ws) {
  int t = blockIdx.x, c = threadIdx.x;
  float acc = 0.f;
  for (int k = 0; k < HID; ++k) acc += aemb[t * HID + k] * bbW[k * HID + c];
  ws[WS_HB + t * HID + c] = acc;
}

// ---------------- rbfW2 = rbf_W @ bb_W ; cvec = rbf_b @ bb_W + bb_b ----------------
__global__ void k_rbfw2(const float* rbfW, const float* rbfb,
                        const float* bbW, const float* bbb, float* ws) {
  int c = threadIdx.x;
  float accs[NRBF];
#pragma unroll
  for (int k = 0; k < NRBF; ++k) accs[k] = 0.f;
  float accb = 0.f;
  for (int m = 0; m < HID; ++m) {
    float w = bbW[m * HID + c];
#pragma unroll
    for (int k = 0; k < NRBF; ++k) accs[k] += rbfW[k * HID + m] * w;
    accb += rbfb[m] * w;
  }
#pragma unroll
  for (int k = 0; k < NRBF; ++k) ws[WS_RBFW2 + k * HID + c] = accs[k];
  ws[WS_CVEC + c] = accb + bbb[c];
}

// ---------------- lat_proj = latents @ sc_W0[128:384] + b0 ----------------
__global__ void k_latproj(const float* latents, const float* scW0,
                          const float* scb0, float* ws) {
  int b = blockIdx.x, t = threadIdx.x;
  __shared__ float lat[LAT];
  lat[t] = latents[b * LAT + t];
  __syncthreads();
  int c0 = 2 * t;
  float a0 = 0.f, a1 = 0.f;
  for (int m = 0; m < LAT; ++m) {
    float2 w = *reinterpret_cast<const float2*>(scW0 + (HID + m) * FCH + c0);
    float lm = lat[m];
    a0 += lm * w.x;
    a1 += lm * w.y;
  }
  ws[WS_LATP + b * FCH + c0] = a0 + scb0[c0];
  ws[WS_LATP + b * FCH + c0 + 1] = a1 + scb0[c0 + 1];
}

// ---------------- per-node geometry ----------------
__global__ void k_node(const float* frac, const float* noise, const int* batch, float* ws) {
  int n = blockIdx.x * blockDim.x + threadIdx.x;
  if (n >= Nn) return;
  int b = batch[n];
  float L[9], Li[9];
#pragma unroll
  for (int i = 0; i < 9; ++i) { L[i] = ws[WS_L + b * 9 + i]; Li[i] = ws[WS_LI + b * 9 + i]; }
  float f0 = frac[n * 3], f1 = frac[n * 3 + 1], f2 = frac[n * 3 + 2];
  float cg[3], p0[3], fp[3], pe[3], fg[3], fd[3];
#pragma unroll
  for (int j = 0; j < 3; ++j) cg[j] = f0 * L[j] + f1 * L[3 + j] + f2 * L[6 + j];
  float sig = ws[WS_SIG + b];
#pragma unroll
  for (int j = 0; j < 3; ++j) p0[j] = cg[j] + sig * noise[n * 3 + j];
#pragma unroll
  for (int j = 0; j < 3; ++j) {
    float v = p0[0] * Li[j] + p0[1] * Li[3 + j] + p0[2] * Li[6 + j];
    fp[j] = v - floorf(v);
  }
#pragma unroll
  for (int j = 0; j < 3; ++j) pe[j] = fp[0] * L[j] + fp[1] * L[3 + j] + fp[2] * L[6 + j];
#pragma unroll
  for (int j = 0; j < 3; ++j) fg[j] = cg[0] * Li[j] + cg[1] * Li[3 + j] + cg[2] * Li[6 + j];
#pragma unroll
  for (int j = 0; j < 3; ++j) { float d = fg[j] - fp[j]; fd[j] = d - rintf(d); }
#pragma unroll
  for (int j = 0; j < 3; ++j) {
    ws[WS_PERT + n * 3 + j] = pe[j];
    ws[WS_ALIGN + n * 3 + j] = pe[j] + fd[0] * L[j] + fd[1] * L[3 + j] + fd[2] * L[6 + j];
  }
}

// ---------------- weight transpose+bf16 convert ----------------
__global__ void k_cvtW0(const float* scW0, unsigned short* w0t) {
  int id = blockIdx.x * blockDim.x + threadIdx.x;   // 512*128 = 65536
  int col = id >> 7, k = id & 127;
  w0t[id] = f2bf(scW0[k * FCH + col]);
}
__global__ void k_cvtW1(const float* scW1, unsigned short* w1t) {
  int id = blockIdx.x * blockDim.x + threadIdx.x;   // 512*512 = 262144
  int col = id >> 9, k = id & 511;
  w1t[id] = f2bf(scW1[k * FCH + col]);
}

// ---------------- the big fused MFMA edge kernel ----------------
// Tile: 32 edges x 512 cols. 4 waves; wave w owns cols [w*128, w*128+128).
// mfma_f32_16x16x32_bf16: A-frag lane l holds A[l&15][8*(l>>4)+e];
// B-frag lane l holds B[8*(l>>4)+e][l&15]; D: col=l&15, row=(l>>4)*4+r.
__global__ __launch_bounds__(256, 3) void k_edge(
    const int* ei, const int* toj, const int* batch, const int* atype,
    const unsigned short* w0t, const unsigned short* w1t,
    const float* scb1, const float* scW2, const float* scb2, float* ws) {
  __shared__ unsigned short s_ef[TE * HID];   // 8 KB, XOR-swizzled rows (256B)
  __shared__ unsigned short s_hh[TE * FCH];   // 32 KB, XOR-swizzled rows (1024B)
  __shared__ float s_latp[FCH];               // 2 KB
  __shared__ float s_rbf[TE][NRBF];           // 2 KB
  __shared__ float s_dvec[TE][3];
  __shared__ float s_dist[TE], s_gtd[TE];
  __shared__ int s_tj[TE], s_ti[TE];
  __shared__ float s_wsum[4][TE];

  char* s_ef_b = (char*)s_ef;
  char* s_hh_b = (char*)s_hh;
  const int t = threadIdx.x;
  const int e0 = blockIdx.x * TE;

  // ---- Phase A: latp staging (all edges in tile share one graph) + geometry
  int b0 = batch[ei[e0]];
  if (t < 128) {
    ((float4*)s_latp)[t] = ((const float4*)(ws + WS_LATP + b0 * FCH))[t];
  }
  if (t < TE) {
    int e = e0 + t;
    int jn = ei[e], iN = ei[Ee + e];
    int b = batch[jn];
    float tx = (float)toj[e * 3], ty = (float)toj[e * 3 + 1], tz = (float)toj[e * 3 + 2];
    const float* L = ws + WS_L + b * 9;
    float dv[3], gv[3];
#pragma unroll
    for (int j = 0; j < 3; ++j) {
      float off = tx * L[j] + ty * L[3 + j] + tz * L[6 + j];
      dv[j] = ws[WS_PERT + iN * 3 + j] - ws[WS_PERT + jn * 3 + j] - off;
      gv[j] = ws[WS_ALIGN + iN * 3 + j] - ws[WS_ALIGN + jn * 3 + j] - off;
    }
    float dist = sqrtf(dv[0] * dv[0] + dv[1] * dv[1] + dv[2] * dv[2]);
    float gtd = sqrtf(gv[0] * gv[0] + gv[1] * gv[1] + gv[2] * gv[2]);
#pragma unroll
    for (int j = 0; j < 3; ++j) s_dvec[t][j] = dv[j];
    s_dist[t] = dist;
    s_gtd[t] = gtd;
    s_tj[t] = atype[jn]; s_ti[t] = atype[iN];
    const float step = 7.0f / 15.0f;
#pragma unroll
    for (int k = 0; k < NRBF; ++k) {
      float d = dist - (float)k * step;
      s_rbf[t][k] = expf(-10.f * d * d);
    }
  }
  __syncthreads();

  // ---- Phase B: ef = silu(hb[tj]+hb[ti]+rbf@rbfW2+cvec) -> bf16 LDS (swizzled)
  {
    int e = t >> 3;              // 0..31
    int c0 = (t & 7) * 16;       // 16 cols per thread
    int tj = s_tj[e], ti = s_ti[e];
    float4 z4[4];
#pragma unroll
    for (int q = 0; q < 4; ++q) {
      float4 a = *(const float4*)(ws + WS_HB + tj * HID + c0 + q * 4);
      float4 bq = *(const float4*)(ws + WS_HB + ti * HID + c0 + q * 4);
      float4 cv = *(const float4*)(ws + WS_CVEC + c0 + q * 4);
      z4[q].x = a.x + bq.x + cv.x; z4[q].y = a.y + bq.y + cv.y;
      z4[q].z = a.z + bq.z + cv.z; z4[q].w = a.w + bq.w + cv.w;
    }
#pragma unroll
    for (int k = 0; k < NRBF; ++k) {
      float rbk = s_rbf[e][k];
#pragma unroll
      for (int q = 0; q < 4; ++q) {
        float4 wv = *(const float4*)(ws + WS_RBFW2 + k * HID + c0 + q * 4);
        z4[q].x += rbk * wv.x; z4[q].y += rbk * wv.y;
        z4[q].z += rbk * wv.z; z4[q].w += rbk * wv.w;
      }
    }
    u16x8 o0, o1;
#pragma unroll
    for (int q = 0; q < 4; ++q) {
      float zz[4] = {z4[q].x, z4[q].y, z4[q].z, z4[q].w};
#pragma unroll
      for (int j = 0; j < 4; ++j) {
        float z = zz[j];
        float sv = z / (1.f + expf(-z));
        unsigned short us = f2bf(sv);
        if (q < 2) o0[q * 4 + j] = us; else o1[(q - 2) * 4 + j] = us;
      }
    }
    int base = e * 256 + c0 * 2;
    int sw = (e & 7) << 4;
    *(u16x8*)(s_ef_b + ((base) ^ sw)) = o0;
    *(u16x8*)(s_ef_b + ((base + 16) ^ sw)) = o1;
  }
  __syncthreads();

  const int lane = t & 63;
  const int wv = t >> 6;
  const int c0w = wv * 128;
  const int lr = lane & 15;     // col (D) / row (A) index
  const int lq = lane >> 4;     // k-quadrant

  // ---- Phase C: GEMM1  hh = relu(ef @ W0a + latp), bf16 -> LDS (swizzled)
  {
    f32x4 acc[2][8];
#pragma unroll
    for (int m = 0; m < 2; ++m)
#pragma unroll
      for (int n = 0; n < 8; ++n) acc[m][n] = (f32x4){0.f, 0.f, 0.f, 0.f};
#pragma unroll
    for (int k0 = 0; k0 < HID; k0 += 32) {
      bf16x8 a[2];
#pragma unroll
      for (int m = 0; m < 2; ++m) {
        int row = m * 16 + lr;
        int off = (row * 256 + (k0 + lq * 8) * 2) ^ ((row & 7) << 4);
        a[m] = *(const bf16x8*)(s_ef_b + off);
      }
#pragma unroll
      for (int n = 0; n < 8; ++n) {
        bf16x8 bfr = *(const bf16x8*)(w0t + (c0w + n * 16 + lr) * HID + k0 + lq * 8);
        acc[0][n] = __builtin_amdgcn_mfma_f32_16x16x32_bf16(a[0], bfr, acc[0][n], 0, 0, 0);
        acc[1][n] = __builtin_amdgcn_mfma_f32_16x16x32_bf16(a[1], bfr, acc[1][n], 0, 0, 0);
      }
    }
#pragma unroll
    for (int m = 0; m < 2; ++m)
#pragma unroll
      for (int n = 0; n < 8; ++n) {
        int col = c0w + n * 16 + lr;
        float lp = s_latp[col];
        f32x4 v = acc[m][n];
#pragma unroll
        for (int r = 0; r < 4; ++r) {
          int row = m * 16 + lq * 4 + r;
          float h = fmaxf(v[r] + lp, 0.f);
          int off = (row * 1024 + col * 2) ^ ((row & 7) << 4);
          *(unsigned short*)(s_hh_b + off) = f2bf(h);
        }
      }
  }
  __syncthreads();

  // ---- Phase D: GEMM2 + fused score reduction
  {
    f32x4 acc[2][8];
#pragma unroll
    for (int m = 0; m < 2; ++m)
#pragma unroll
      for (int n = 0; n < 8; ++n) acc[m][n] = (f32x4){0.f, 0.f, 0.f, 0.f};
#pragma unroll 2
    for (int k0 = 0; k0 < FCH; k0 += 32) {
      bf16x8 a[2];
#pragma unroll
      for (int m = 0; m < 2; ++m) {
        int row = m * 16 + lr;
        int off = (row * 1024 + (k0 + lq * 8) * 2) ^ ((row & 7) << 4);
        a[m] = *(const bf16x8*)(s_hh_b + off);
      }
#pragma unroll
      for (int n = 0; n < 8; ++n) {
        bf16x8 bfr = *(const bf16x8*)(w1t + (c0w + n * 16 + lr) * FCH + k0 + lq * 8);
        acc[0][n] = __builtin_amdgcn_mfma_f32_16x16x32_bf16(a[0], bfr, acc[0][n], 0, 0, 0);
        acc[1][n] = __builtin_amdgcn_mfma_f32_16x16x32_bf16(a[1], bfr, acc[1][n], 0, 0, 0);
      }
    }
    // hh1 = relu(acc + b1); p += hh1 * W2   (per lane: 8 cols x 8 rows)
    float p[2][4];
#pragma unroll
    for (int m = 0; m < 2; ++m)
#pragma unroll
      for (int r = 0; r < 4; ++r) p[m][r] = 0.f;
#pragma unroll
    for (int n = 0; n < 8; ++n) {
      int col = c0w + n * 16 + lr;
      float b1v = scb1[col];
      float w2v = scW2[col];
#pragma unroll
      for (int m = 0; m < 2; ++m) {
        f32x4 v = acc[m][n];
#pragma unroll
        for (int r = 0; r < 4; ++r) p[m][r] += fmaxf(v[r] + b1v, 0.f) * w2v;
      }
    }
    // reduce over the 16 lanes sharing a row (lane bits 0..3)
#pragma unroll
    for (int m = 0; m < 2; ++m)
#pragma unroll
      for (int r = 0; r < 4; ++r) {
        float x = p[m][r];
        x += __shfl_xor(x, 1);
        x += __shfl_xor(x, 2);
        x += __shfl_xor(x, 4);
        x += __shfl_xor(x, 8);
        p[m][r] = x;
      }
    if (lr == 0) {
#pragma unroll
      for (int m = 0; m < 2; ++m)
#pragma unroll
        for (int r = 0; r < 4; ++r) s_wsum[wv][m * 16 + lq * 4 + r] = p[m][r];
    }
  }
  __syncthreads();

  // ---- Phase E: segment-mean scatter (threads 0..31)
  if (t < TE) {
    int e = e0 + t;
    float score = scb2[0] + s_wsum[0][t] + s_wsum[1][t] + s_wsum[2][t] + s_wsum[3][t];
    int jn = ei[e], iN = ei[Ee + e];
    int s = e;
    while (s > 0 && ei[s - 1] == jn && ei[Ee + s - 1] == iN) --s;
    int en = e;
    while (en + 1 < Ee && ei[en + 1] == jn && ei[Ee + en + 1] == iN) ++en;
    float invc = 1.f / (float)(en - s + 1);
    float dist = s_dist[t];
    float denom = dist + 1e-8f;
    float gts = s_gtd[t] - dist;
#pragma unroll
    for (int j = 0; j < 3; ++j) {
      float dir = s_dvec[t][j] / denom;
      atomicAdd(&ws[WS_SN + iN * 3 + j], score * dir * invc);
      atomicAdd(&ws[WS_GN + iN * 3 + j], gts * dir * invc);
    }
  }
}

// ---------------- per-node: loss terms, preds, center sums ----------------
__global__ void k_node2(const int* batch, float* ws) {
  int n = blockIdx.x * blockDim.x + threadIdx.x;
  if (n >= Nn) return;
  int b = batch[n];
  float sig = ws[WS_SIG + b];
#pragma unroll
  for (int j = 0; j < 3; ++j) {
    float s = ws[WS_SN + n * 3 + j], g = ws[WS_GN + n * 3 + j];
    float d = s - g / sig;
    atomicAdd(&ws[WS_BSUM + b * 3 + j], d * d);
    float pr = ws[WS_PERT + n * 3 + j] + s / sig;
    ws[WS_PREDS + n * 3 + j] = pr;
    atomicAdd(&ws[WS_CENTER + b * 3 + j], pr);
  }
}

// ---------------- per-node: global min/max of dc ----------------
__global__ void k_minmax(const int* batch, const int* num_atoms, float* ws) {
  int n = blockIdx.x * blockDim.x + threadIdx.x;
  int lane = threadIdx.x & 63, wid = threadIdx.x >> 6;
  float mx[3], mn[3];
  if (n < Nn) {
    int b = batch[n];
    float na = (float)num_atoms[b];
#pragma unroll
    for (int j = 0; j < 3; ++j) {
      float v = ws[WS_PREDS + n * 3 + j] - ws[WS_CENTER + b * 3 + j] / na;
      mx[j] = v; mn[j] = v;
    }
  } else {
#pragma unroll
    for (int j = 0; j < 3; ++j) { mx[j] = -3.0e38f; mn[j] = 3.0e38f; }
  }
#pragma unroll
  for (int off = 32; off >= 1; off >>= 1) {
#pragma unroll
    for (int j = 0; j < 3; ++j) {
      mx[j] = fmaxf(mx[j], __shfl_xor(mx[j], off));
      mn[j] = fminf(mn[j], __shfl_xor(mn[j], off));
    }
  }
  __shared__ float smx[4][3], smn[4][3];
  if (lane == 0) {
#pragma unroll
    for (int j = 0; j < 3; ++j) { smx[wid][j] = mx[j]; smn[wid][j] = mn[j]; }
  }
  __syncthreads();
  if (threadIdx.x == 0) {
#pragma unroll
    for (int j = 0; j < 3; ++j) {
      float M = fmaxf(fmaxf(smx[0][j], smx[1][j]), fmaxf(smx[2][j], smx[3][j]));
      float m = fminf(fminf(smn[0][j], smn[1][j]), fminf(smn[2][j], smn[3][j]));
      atomicMaxFloat(&ws[WS_MINMAX + j], M);
      atomicMinFloat(&ws[WS_MINMAX + 3 + j], m);
    }
  }
}

// ---------------- finalize ----------------
__global__ void k_final(const int* num_atoms, const float* ws, float* out) {
  float loss = 0.f;
  for (int b = 0; b < Bb; ++b) {
    float na = (float)num_atoms[b];
    for (int j = 0; j < 3; ++j) loss += ws[WS_BSUM + b * 3 + j] / na;
  }
  loss /= (3.0f * (float)Bb);
  float pbs = fabsf(ws[WS_MINMAX + 0] + ws[WS_MINMAX + 3]) +
              fabsf(ws[WS_MINMAX + 1] + ws[WS_MINMAX + 4]) +
              fabsf(ws[WS_MINMAX + 2] + ws[WS_MINMAX + 5]);
  out[0] = loss;
  out[1] = pbs;
}

extern "C" void kernel_launch(void* const* d_in, const int* in_sizes, int n_in,
                              void* d_out, int out_size, void* d_ws, size_t ws_size,
                              hipStream_t stream) {
  const float* latents = (const float*)d_in[0];
  const float* gtf     = (const float*)d_in[1];
  const float* lengths = (const float*)d_in[2];
  const float* angles  = (const float*)d_in[3];
  const float* noise   = (const float*)d_in[4];
  const float* sigmas  = (const float*)d_in[5];
  const float* aemb    = (const float*)d_in[6];
  const float* rbfW    = (const float*)d_in[7];
  const float* rbfb    = (const float*)d_in[8];
  const float* bbW     = (const float*)d_in[9];
  const float* bbb     = (const float*)d_in[10];
  const float* scW0    = (const float*)d_in[11];
  const float* scb0    = (const float*)d_in[12];
  const float* scW1    = (const float*)d_in[13];
  const float* scb1    = (const float*)d_in[14];
  const float* scW2    = (const float*)d_in[15];
  const float* scb2    = (const float*)d_in[16];
  const int* num_atoms = (const int*)d_in[17];
  const int* atype     = (const int*)d_in[18];
  const int* batch     = (const int*)d_in[19];
  const int* ei        = (const int*)d_in[20];
  const int* toj       = (const int*)d_in[21];
  const int* tsteps    = (const int*)d_in[22];
  float* ws = (float*)d_ws;
  float* out = (float*)d_out;
  unsigned short* w0t = (unsigned short*)(ws + WS_W0T_F);
  unsigned short* w1t = (unsigned short*)(ws + WS_W1T_F);

  hipLaunchKernelGGL(k_init, dim3(256), dim3(256), 0, stream, ws);
  hipLaunchKernelGGL(k_lattice, dim3(1), dim3(128), 0, stream, lengths, angles, sigmas, tsteps, ws);
  hipLaunchKernelGGL(k_hb, dim3(100), dim3(128), 0, stream, aemb, bbW, ws);
  hipLaunchKernelGGL(k_rbfw2, dim3(1), dim3(128), 0, stream, rbfW, rbfb, bbW, bbb, ws);
  hipLaunchKernelGGL(k_latproj, dim3(128), dim3(256), 0, stream, latents, scW0, scb0, ws);
  hipLaunchKernelGGL(k_node, dim3(50), dim3(256), 0, stream, gtf, noise, batch, ws);
  hipLaunchKernelGGL(k_cvtW0, dim3(256), dim3(256), 0, stream, scW0, w0t);
  hipLaunchKernelGGL(k_cvtW1, dim3(1024), dim3(256), 0, stream, scW1, w1t);
  hipLaunchKernelGGL(k_edge, dim3(Ee / TE), dim3(256), 0, stream,
                     ei, toj, batch, atype, w0t, w1t, scb1, scW2, scb2, ws);
  hipLaunchKernelGGL(k_node2, dim3(50), dim3(256), 0, stream, batch, ws);
  hipLaunchKernelGGL(k_minmax, dim3(50), dim3(256), 0, stream, batch, num_atoms, ws);
  hipLaunchKernelGGL(k_final, dim3(1), dim3(1), 0, stream, num_atoms, ws, out);
}

// Round 3
// 554.210 us; speedup vs baseline: 5.0583x; 1.6929x over previous
//
#include <hip/hip_runtime.h>
#include <hip/hip_bf16.h>

// ---------------- problem constants ----------------
namespace {
constexpr int Bb = 128, Nn = 12800, Ee = 262144;
constexpr int LAT = 256, HID = 128, FCH = 512, NRBF = 16;
constexpr int TE = 32; // edges per block in edge kernel (divides 2048 = edges/graph)

// workspace offsets (floats)
constexpr int WS_L      = 0;        // B*9
constexpr int WS_LI     = 1152;     // B*9
constexpr int WS_SIG    = 2304;     // B
constexpr int WS_RBFW2  = 2432;     // 16*128
constexpr int WS_CVEC   = 4480;     // 128
constexpr int WS_HB     = 4608;     // 100*128
constexpr int WS_LATP   = 17408;    // B*512
constexpr int WS_PERT   = 82944;    // N*3
constexpr int WS_ALIGN  = 121344;   // N*3
constexpr int WS_SN     = 159744;   // N*3 (atomic)
constexpr int WS_GN     = 198144;   // N*3 (atomic)
constexpr int WS_PREDS  = 236544;   // N*3
constexpr int WS_BSUM   = 274944;   // B*3 (atomic)
constexpr int WS_CENTER = 275328;   // B*3 (atomic)
constexpr int WS_MINMAX = 275712;   // 6   (max x3, min x3)
// bf16 fragment-tiled weights (stored as ushort), float-index base:
constexpr int WS_W0T_F  = 276000;   // ushort[512*128]  (= 32768 floats)
constexpr int WS_W1T_F  = 308768;   // ushort[512*512]  (= 131072 floats)
}

typedef short bf16x8 __attribute__((ext_vector_type(8)));
typedef unsigned short u16x8 __attribute__((ext_vector_type(8)));
typedef float f32x4 __attribute__((ext_vector_type(4)));

static __device__ __forceinline__ unsigned short f2bf(float f) {
  unsigned int u = __float_as_uint(f);
  unsigned int r = (u + 0x7fffu + ((u >> 16) & 1u)) >> 16;
  return (unsigned short)r;
}

static __device__ __forceinline__ void atomicMaxFloat(float* addr, float val) {
  int* ai = reinterpret_cast<int*>(addr);
  int old = *ai;
  while (__int_as_float(old) < val) {
    int assumed = old;
    old = atomicCAS(ai, assumed, __float_as_int(val));
    if (old == assumed) break;
  }
}
static __device__ __forceinline__ void atomicMinFloat(float* addr, float val) {
  int* ai = reinterpret_cast<int*>(addr);
  int old = *ai;
  while (__int_as_float(old) > val) {
    int assumed = old;
    old = atomicCAS(ai, assumed, __float_as_int(val));
    if (old == assumed) break;
  }
}

// ---------------- init: zero accumulators, init minmax ----------------
__global__ void k_init(float* ws) {
  int i = blockIdx.x * blockDim.x + threadIdx.x;
  int stride = gridDim.x * blockDim.x;
  for (int k = i; k < 2 * Nn * 3; k += stride) ws[WS_SN + k] = 0.f;
  for (int k = i; k < 2 * Bb * 3; k += stride) ws[WS_BSUM + k] = 0.f;
  if (i < 3) ws[WS_MINMAX + i] = -3.0e38f;
  else if (i < 6) ws[WS_MINMAX + i] = 3.0e38f;
}

// ---------------- lattice, inverse, sigma per batch ----------------
__global__ void k_lattice(const float* lengths, const float* angles,
                          const float* sigmas, const int* tsteps, float* ws) {
  int b = threadIdx.x;
  if (b >= Bb) return;
  float a = lengths[b * 3 + 0], bl = lengths[b * 3 + 1], c = lengths[b * 3 + 2];
  const float d2r = 0.017453292519943295f;
  float al = angles[b * 3 + 0] * d2r, be = angles[b * 3 + 1] * d2r, ga = angles[b * 3 + 2] * d2r;
  float ca = cosf(al), cb = cosf(be), cg = cosf(ga), sa = sinf(al), sb = sinf(be);
  float val = (ca * cb - cg) / (sa * sb);
  val = fminf(1.f, fmaxf(-1.f, val));
  float gs = acosf(val);
  float L[3][3];
  L[0][0] = a * sb;              L[0][1] = 0.f;                L[0][2] = a * cb;
  L[1][0] = -bl * sa * cosf(gs); L[1][1] = bl * sa * sinf(gs); L[1][2] = bl * ca;
  L[2][0] = 0.f;                 L[2][1] = 0.f;                L[2][2] = c;
  float c00 = L[1][1] * L[2][2] - L[1][2] * L[2][1];
  float c01 = -(L[1][0] * L[2][2] - L[1][2] * L[2][0]);
  float c02 = L[1][0] * L[2][1] - L[1][1] * L[2][0];
  float det = L[0][0] * c00 + L[0][1] * c01 + L[0][2] * c02;
  float id = 1.f / det;
  float inv[3][3];
  inv[0][0] =  (L[1][1]*L[2][2] - L[1][2]*L[2][1]) * id;
  inv[0][1] = -(L[0][1]*L[2][2] - L[0][2]*L[2][1]) * id;
  inv[0][2] =  (L[0][1]*L[1][2] - L[0][2]*L[1][1]) * id;
  inv[1][0] = -(L[1][0]*L[2][2] - L[1][2]*L[2][0]) * id;
  inv[1][1] =  (L[0][0]*L[2][2] - L[0][2]*L[2][0]) * id;
  inv[1][2] = -(L[0][0]*L[1][2] - L[0][2]*L[1][0]) * id;
  inv[2][0] =  (L[1][0]*L[2][1] - L[1][1]*L[2][0]) * id;
  inv[2][1] = -(L[0][0]*L[2][1] - L[0][1]*L[2][0]) * id;
  inv[2][2] =  (L[0][0]*L[1][1] - L[0][1]*L[1][0]) * id;
  for (int i = 0; i < 3; ++i)
    for (int j = 0; j < 3; ++j) {
      ws[WS_L + b * 9 + i * 3 + j] = L[i][j];
      ws[WS_LI + b * 9 + i * 3 + j] = inv[i][j];
    }
  ws[WS_SIG + b] = sigmas[tsteps[b]];
}

// ---------------- hb = atom_emb @ bb_W ----------------
__global__ void k_hb(const float* aemb, const float* bbW, float* ws) {
  int t = blockIdx.x, c = threadIdx.x;
  float acc = 0.f;
  for (int k = 0; k < HID; ++k) acc += aemb[t * HID + k] * bbW[k * HID + c];
  ws[WS_HB + t * HID + c] = acc;
}

// ---------------- rbfW2 = rbf_W @ bb_W ; cvec = rbf_b @ bb_W + bb_b ----------------
__global__ void k_rbfw2(const float* rbfW, const float* rbfb,
                        const float* bbW, const float* bbb, float* ws) {
  int c = threadIdx.x;
  float accs[NRBF];
#pragma unroll
  for (int k = 0; k < NRBF; ++k) accs[k] = 0.f;
  float accb = 0.f;
  for (int m = 0; m < HID; ++m) {
    float w = bbW[m * HID + c];
#pragma unroll
    for (int k = 0; k < NRBF; ++k) accs[k] += rbfW[k * HID + m] * w;
    accb += rbfb[m] * w;
  }
#pragma unroll
  for (int k = 0; k < NRBF; ++k) ws[WS_RBFW2 + k * HID + c] = accs[k];
  ws[WS_CVEC + c] = accb + bbb[c];
}

// ---------------- lat_proj = latents @ sc_W0[128:384] + b0 ----------------
__global__ void k_latproj(const float* latents, const float* scW0,
                          const float* scb0, float* ws) {
  int b = blockIdx.x, t = threadIdx.x;
  __shared__ float lat[LAT];
  lat[t] = latents[b * LAT + t];
  __syncthreads();
  int c0 = 2 * t;
  float a0 = 0.f, a1 = 0.f;
  for (int m = 0; m < LAT; ++m) {
    float2 w = *reinterpret_cast<const float2*>(scW0 + (HID + m) * FCH + c0);
    float lm = lat[m];
    a0 += lm * w.x;
    a1 += lm * w.y;
  }
  ws[WS_LATP + b * FCH + c0] = a0 + scb0[c0];
  ws[WS_LATP + b * FCH + c0 + 1] = a1 + scb0[c0 + 1];
}

// ---------------- per-node geometry ----------------
__global__ void k_node(const float* frac, const float* noise, const int* batch, float* ws) {
  int n = blockIdx.x * blockDim.x + threadIdx.x;
  if (n >= Nn) return;
  int b = batch[n];
  float L[9], Li[9];
#pragma unroll
  for (int i = 0; i < 9; ++i) { L[i] = ws[WS_L + b * 9 + i]; Li[i] = ws[WS_LI + b * 9 + i]; }
  float f0 = frac[n * 3], f1 = frac[n * 3 + 1], f2 = frac[n * 3 + 2];
  float cg[3], p0[3], fp[3], pe[3], fg[3], fd[3];
#pragma unroll
  for (int j = 0; j < 3; ++j) cg[j] = f0 * L[j] + f1 * L[3 + j] + f2 * L[6 + j];
  float sig = ws[WS_SIG + b];
#pragma unroll
  for (int j = 0; j < 3; ++j) p0[j] = cg[j] + sig * noise[n * 3 + j];
#pragma unroll
  for (int j = 0; j < 3; ++j) {
    float v = p0[0] * Li[j] + p0[1] * Li[3 + j] + p0[2] * Li[6 + j];
    fp[j] = v - floorf(v);
  }
#pragma unroll
  for (int j = 0; j < 3; ++j) pe[j] = fp[0] * L[j] + fp[1] * L[3 + j] + fp[2] * L[6 + j];
#pragma unroll
  for (int j = 0; j < 3; ++j) fg[j] = cg[0] * Li[j] + cg[1] * Li[3 + j] + cg[2] * Li[6 + j];
#pragma unroll
  for (int j = 0; j < 3; ++j) { float d = fg[j] - fp[j]; fd[j] = d - rintf(d); }
#pragma unroll
  for (int j = 0; j < 3; ++j) {
    ws[WS_PERT + n * 3 + j] = pe[j];
    ws[WS_ALIGN + n * 3 + j] = pe[j] + fd[0] * L[j] + fd[1] * L[3 + j] + fd[2] * L[6 + j];
  }
}

// ---------------- weight convert into MFMA-fragment-tiled bf16 ----------------
// Layout: tile (colTile, kTile) of 16 cols x 32 ks stored as 64 lanes x 8 shorts:
//   idx = (tile * 64 + lane) * 8 + e ; lane e holds W[kTile*32+(lane>>4)*8+e][colTile*16+(lane&15)]
__global__ void k_cvtW0(const float* scW0, unsigned short* w0t) {
  int id = blockIdx.x * blockDim.x + threadIdx.x;   // 65536
  int e = id & 7, lane = (id >> 3) & 63, tile = id >> 9;  // tile = colTile*4 + kTile
  int colTile = tile >> 2, kTile = tile & 3;
  int col = colTile * 16 + (lane & 15);
  int k = kTile * 32 + (lane >> 4) * 8 + e;
  w0t[id] = f2bf(scW0[k * FCH + col]);
}
__global__ void k_cvtW1(const float* scW1, unsigned short* w1t) {
  int id = blockIdx.x * blockDim.x + threadIdx.x;   // 262144
  int e = id & 7, lane = (id >> 3) & 63, tile = id >> 9;  // tile = colTile*16 + kTile
  int colTile = tile >> 4, kTile = tile & 15;
  int col = colTile * 16 + (lane & 15);
  int k = kTile * 32 + (lane >> 4) * 8 + e;
  w1t[id] = f2bf(scW1[k * FCH + col]);
}

// ---------------- the big fused MFMA edge kernel ----------------
// Tile: 32 edges x 512 cols. 4 waves; wave w owns cols [w*128, w*128+128).
// mfma_f32_16x16x32_bf16: A-frag lane l holds A[l&15][8*(l>>4)+e];
// B-frag lane l holds B[8*(l>>4)+e][l&15]; D: col=l&15, row=(l>>4)*4+r.
__global__ __launch_bounds__(256, 3) void k_edge(
    const int* ei, const int* toj, const int* batch, const int* atype,
    const unsigned short* w0t, const unsigned short* w1t,
    const float* scb1, const float* scW2, const float* scb2, float* ws) {
  __shared__ unsigned short s_ef[TE * HID];   // 8 KB, XOR-swizzled rows (256B)
  __shared__ unsigned short s_hh[TE * FCH];   // 32 KB, XOR-swizzled rows (1024B)
  __shared__ float s_latp[FCH];               // 2 KB
  __shared__ float s_rbf[TE][NRBF];           // 2 KB
  __shared__ float s_dvec[TE][3];
  __shared__ float s_dist[TE], s_gtd[TE];
  __shared__ int s_tj[TE], s_ti[TE];
  __shared__ float s_wsum[4][TE];

  char* s_ef_b = (char*)s_ef;
  char* s_hh_b = (char*)s_hh;
  const int t = threadIdx.x;
  const int e0 = blockIdx.x * TE;

  // ---- Phase A: latp staging (all edges in tile share one graph) + geometry
  int b0 = batch[ei[e0]];
  if (t < 128) {
    ((float4*)s_latp)[t] = ((const float4*)(ws + WS_LATP + b0 * FCH))[t];
  }
  if (t < TE) {
    int e = e0 + t;
    int jn = ei[e], iN = ei[Ee + e];
    int b = batch[jn];
    float tx = (float)toj[e * 3], ty = (float)toj[e * 3 + 1], tz = (float)toj[e * 3 + 2];
    const float* L = ws + WS_L + b * 9;
    float dv[3], gv[3];
#pragma unroll
    for (int j = 0; j < 3; ++j) {
      float off = tx * L[j] + ty * L[3 + j] + tz * L[6 + j];
      dv[j] = ws[WS_PERT + iN * 3 + j] - ws[WS_PERT + jn * 3 + j] - off;
      gv[j] = ws[WS_ALIGN + iN * 3 + j] - ws[WS_ALIGN + jn * 3 + j] - off;
    }
    float dist = sqrtf(dv[0] * dv[0] + dv[1] * dv[1] + dv[2] * dv[2]);
    float gtd = sqrtf(gv[0] * gv[0] + gv[1] * gv[1] + gv[2] * gv[2]);
#pragma unroll
    for (int j = 0; j < 3; ++j) s_dvec[t][j] = dv[j];
    s_dist[t] = dist;
    s_gtd[t] = gtd;
    s_tj[t] = atype[jn]; s_ti[t] = atype[iN];
    const float step = 7.0f / 15.0f;
#pragma unroll
    for (int k = 0; k < NRBF; ++k) {
      float d = dist - (float)k * step;
      s_rbf[t][k] = expf(-10.f * d * d);
    }
  }
  __syncthreads();

  // ---- Phase B: ef = silu(hb[tj]+hb[ti]+rbf@rbfW2+cvec) -> bf16 LDS (swizzled)
  {
    int e = t >> 3;              // 0..31
    int c0 = (t & 7) * 16;       // 16 cols per thread
    int tj = s_tj[e], ti = s_ti[e];
    float4 z4[4];
#pragma unroll
    for (int q = 0; q < 4; ++q) {
      float4 a = *(const float4*)(ws + WS_HB + tj * HID + c0 + q * 4);
      float4 bq = *(const float4*)(ws + WS_HB + ti * HID + c0 + q * 4);
      float4 cv = *(const float4*)(ws + WS_CVEC + c0 + q * 4);
      z4[q].x = a.x + bq.x + cv.x; z4[q].y = a.y + bq.y + cv.y;
      z4[q].z = a.z + bq.z + cv.z; z4[q].w = a.w + bq.w + cv.w;
    }
#pragma unroll
    for (int k = 0; k < NRBF; ++k) {
      float rbk = s_rbf[e][k];
#pragma unroll
      for (int q = 0; q < 4; ++q) {
        float4 wv = *(const float4*)(ws + WS_RBFW2 + k * HID + c0 + q * 4);
        z4[q].x += rbk * wv.x; z4[q].y += rbk * wv.y;
        z4[q].z += rbk * wv.z; z4[q].w += rbk * wv.w;
      }
    }
    u16x8 o0, o1;
#pragma unroll
    for (int q = 0; q < 4; ++q) {
      float zz[4] = {z4[q].x, z4[q].y, z4[q].z, z4[q].w};
#pragma unroll
      for (int j = 0; j < 4; ++j) {
        float z = zz[j];
        float sv = z / (1.f + expf(-z));
        unsigned short us = f2bf(sv);
        if (q < 2) o0[q * 4 + j] = us; else o1[(q - 2) * 4 + j] = us;
      }
    }
    int base = e * 256 + c0 * 2;
    int sw = (e & 7) << 4;
    *(u16x8*)(s_ef_b + ((base) ^ sw)) = o0;
    *(u16x8*)(s_ef_b + ((base + 16) ^ sw)) = o1;
  }
  __syncthreads();

  const int lane = t & 63;
  const int wv = t >> 6;
  const int c0w = wv * 128;
  const int lr = lane & 15;     // col (D) / row (A) index
  const int lq = lane >> 4;     // k-quadrant

  // ---- Phase C: GEMM1  hh = relu(ef @ W0a + latp), bf16 -> LDS (swizzled)
  {
    f32x4 acc[2][8];
#pragma unroll
    for (int m = 0; m < 2; ++m)
#pragma unroll
      for (int n = 0; n < 8; ++n) acc[m][n] = (f32x4){0.f, 0.f, 0.f, 0.f};
    // fragment-tiled W0: wave's colTiles are wv*8+n, kTiles 0..3
    const unsigned short* w0base = w0t + (size_t)(wv * 8) * 4 * 512 + lane * 8;
#pragma unroll
    for (int kt = 0; kt < 4; ++kt) {
      bf16x8 a[2];
#pragma unroll
      for (int m = 0; m < 2; ++m) {
        int row = m * 16 + lr;
        int off = (row * 256 + (kt * 32 + lq * 8) * 2) ^ ((row & 7) << 4);
        a[m] = *(const bf16x8*)(s_ef_b + off);
      }
#pragma unroll
      for (int n = 0; n < 8; ++n) {
        bf16x8 bfr = *(const bf16x8*)(w0base + (n * 4 + kt) * 512);
        acc[0][n] = __builtin_amdgcn_mfma_f32_16x16x32_bf16(a[0], bfr, acc[0][n], 0, 0, 0);
        acc[1][n] = __builtin_amdgcn_mfma_f32_16x16x32_bf16(a[1], bfr, acc[1][n], 0, 0, 0);
      }
    }
#pragma unroll
    for (int m = 0; m < 2; ++m)
#pragma unroll
      for (int n = 0; n < 8; ++n) {
        int col = c0w + n * 16 + lr;
        float lp = s_latp[col];
        f32x4 v = acc[m][n];
#pragma unroll
        for (int r = 0; r < 4; ++r) {
          int row = m * 16 + lq * 4 + r;
          float h = fmaxf(v[r] + lp, 0.f);
          int off = (row * 1024 + col * 2) ^ ((row & 7) << 4);
          *(unsigned short*)(s_hh_b + off) = f2bf(h);
        }
      }
  }
  __syncthreads();

  // ---- Phase D: GEMM2 + fused score reduction
  {
    f32x4 acc[2][8];
#pragma unroll
    for (int m = 0; m < 2; ++m)
#pragma unroll
      for (int n = 0; n < 8; ++n) acc[m][n] = (f32x4){0.f, 0.f, 0.f, 0.f};
    const unsigned short* w1base = w1t + (size_t)(wv * 8) * 16 * 512 + lane * 8;
#pragma unroll 4
    for (int kt = 0; kt < 16; ++kt) {
      bf16x8 a[2];
#pragma unroll
      for (int m = 0; m < 2; ++m) {
        int row = m * 16 + lr;
        int off = (row * 1024 + (kt * 32 + lq * 8) * 2) ^ ((row & 7) << 4);
        a[m] = *(const bf16x8*)(s_hh_b + off);
      }
#pragma unroll
      for (int n = 0; n < 8; ++n) {
        bf16x8 bfr = *(const bf16x8*)(w1base + (n * 16 + kt) * 512);
        acc[0][n] = __builtin_amdgcn_mfma_f32_16x16x32_bf16(a[0], bfr, acc[0][n], 0, 0, 0);
        acc[1][n] = __builtin_amdgcn_mfma_f32_16x16x32_bf16(a[1], bfr, acc[1][n], 0, 0, 0);
      }
    }
    // hh1 = relu(acc + b1); p += hh1 * W2   (per lane: 8 cols x 8 rows)
    float p[2][4];
#pragma unroll
    for (int m = 0; m < 2; ++m)
#pragma unroll
      for (int r = 0; r < 4; ++r) p[m][r] = 0.f;
#pragma unroll
    for (int n = 0; n < 8; ++n) {
      int col = c0w + n * 16 + lr;
      float b1v = scb1[col];
      float w2v = scW2[col];
#pragma unroll
      for (int m = 0; m < 2; ++m) {
        f32x4 v = acc[m][n];
#pragma unroll
        for (int r = 0; r < 4; ++r) p[m][r] += fmaxf(v[r] + b1v, 0.f) * w2v;
      }
    }
    // reduce over the 16 lanes sharing a row (lane bits 0..3)
#pragma unroll
    for (int m = 0; m < 2; ++m)
#pragma unroll
      for (int r = 0; r < 4; ++r) {
        float x = p[m][r];
        x += __shfl_xor(x, 1);
        x += __shfl_xor(x, 2);
        x += __shfl_xor(x, 4);
        x += __shfl_xor(x, 8);
        p[m][r] = x;
      }
    if (lr == 0) {
#pragma unroll
      for (int m = 0; m < 2; ++m)
#pragma unroll
        for (int r = 0; r < 4; ++r) s_wsum[wv][m * 16 + lq * 4 + r] = p[m][r];
    }
  }
  __syncthreads();

  // ---- Phase E: segment-mean scatter (threads 0..31)
  if (t < TE) {
    int e = e0 + t;
    float score = scb2[0] + s_wsum[0][t] + s_wsum[1][t] + s_wsum[2][t] + s_wsum[3][t];
    int jn = ei[e], iN = ei[Ee + e];
    int s = e;
    while (s > 0 && ei[s - 1] == jn && ei[Ee + s - 1] == iN) --s;
    int en = e;
    while (en + 1 < Ee && ei[en + 1] == jn && ei[Ee + en + 1] == iN) ++en;
    float invc = 1.f / (float)(en - s + 1);
    float dist = s_dist[t];
    float denom = dist + 1e-8f;
    float gts = s_gtd[t] - dist;
#pragma unroll
    for (int j = 0; j < 3; ++j) {
      float dir = s_dvec[t][j] / denom;
      atomicAdd(&ws[WS_SN + iN * 3 + j], score * dir * invc);
      atomicAdd(&ws[WS_GN + iN * 3 + j], gts * dir * invc);
    }
  }
}

// ---------------- per-node: loss terms, preds, center sums ----------------
__global__ void k_node2(const int* batch, float* ws) {
  int n = blockIdx.x * blockDim.x + threadIdx.x;
  if (n >= Nn) return;
  int b = batch[n];
  float sig = ws[WS_SIG + b];
#pragma unroll
  for (int j = 0; j < 3; ++j) {
    float s = ws[WS_SN + n * 3 + j], g = ws[WS_GN + n * 3 + j];
    float d = s - g / sig;
    atomicAdd(&ws[WS_BSUM + b * 3 + j], d * d);
    float pr = ws[WS_PERT + n * 3 + j] + s / sig;
    ws[WS_PREDS + n * 3 + j] = pr;
    atomicAdd(&ws[WS_CENTER + b * 3 + j], pr);
  }
}

// ---------------- per-node: global min/max of dc ----------------
__global__ void k_minmax(const int* batch, const int* num_atoms, float* ws) {
  int n = blockIdx.x * blockDim.x + threadIdx.x;
  int lane = threadIdx.x & 63, wid = threadIdx.x >> 6;
  float mx[3], mn[3];
  if (n < Nn) {
    int b = batch[n];
    float na = (float)num_atoms[b];
#pragma unroll
    for (int j = 0; j < 3; ++j) {
      float v = ws[WS_PREDS + n * 3 + j] - ws[WS_CENTER + b * 3 + j] / na;
      mx[j] = v; mn[j] = v;
    }
  } else {
#pragma unroll
    for (int j = 0; j < 3; ++j) { mx[j] = -3.0e38f; mn[j] = 3.0e38f; }
  }
#pragma unroll
  for (int off = 32; off >= 1; off >>= 1) {
#pragma unroll
    for (int j = 0; j < 3; ++j) {
      mx[j] = fmaxf(mx[j], __shfl_xor(mx[j], off));
      mn[j] = fminf(mn[j], __shfl_xor(mn[j], off));
    }
  }
  __shared__ float smx[4][3], smn[4][3];
  if (lane == 0) {
#pragma unroll
    for (int j = 0; j < 3; ++j) { smx[wid][j] = mx[j]; smn[wid][j] = mn[j]; }
  }
  __syncthreads();
  if (threadIdx.x == 0) {
#pragma unroll
    for (int j = 0; j < 3; ++j) {
      float M = fmaxf(fmaxf(smx[0][j], smx[1][j]), fmaxf(smx[2][j], smx[3][j]));
      float m = fminf(fminf(smn[0][j], smn[1][j]), fminf(smn[2][j], smn[3][j]));
      atomicMaxFloat(&ws[WS_MINMAX + j], M);
      atomicMinFloat(&ws[WS_MINMAX + 3 + j], m);
    }
  }
}

// ---------------- finalize (parallel over batches) ----------------
__global__ void k_final(const int* num_atoms, const float* ws, float* out) {
  int t = threadIdx.x;  // 128 threads
  float loss = 0.f;
  if (t < Bb) {
    float na = (float)num_atoms[t];
    loss = (ws[WS_BSUM + t * 3] + ws[WS_BSUM + t * 3 + 1] + ws[WS_BSUM + t * 3 + 2]) / na;
  }
#pragma unroll
  for (int off = 32; off >= 1; off >>= 1) loss += __shfl_xor(loss, off);
  __shared__ float s2[2];
  if ((t & 63) == 0) s2[t >> 6] = loss;
  __syncthreads();
  if (t == 0) {
    float L = (s2[0] + s2[1]) / (3.0f * (float)Bb);
    float pbs = fabsf(ws[WS_MINMAX + 0] + ws[WS_MINMAX + 3]) +
                fabsf(ws[WS_MINMAX + 1] + ws[WS_MINMAX + 4]) +
                fabsf(ws[WS_MINMAX + 2] + ws[WS_MINMAX + 5]);
    out[0] = L;
    out[1] = pbs;
  }
}

extern "C" void kernel_launch(void* const* d_in, const int* in_sizes, int n_in,
                              void* d_out, int out_size, void* d_ws, size_t ws_size,
                              hipStream_t stream) {
  const float* latents = (const float*)d_in[0];
  const float* gtf     = (const float*)d_in[1];
  const float* lengths = (const float*)d_in[2];
  const float* angles  = (const float*)d_in[3];
  const float* noise   = (const float*)d_in[4];
  const float* sigmas  = (const float*)d_in[5];
  const float* aemb    = (const float*)d_in[6];
  const float* rbfW    = (const float*)d_in[7];
  const float* rbfb    = (const float*)d_in[8];
  const float* bbW     = (const float*)d_in[9];
  const float* bbb     = (const float*)d_in[10];
  const float* scW0    = (const float*)d_in[11];
  const float* scb0    = (const float*)d_in[12];
  const float* scW1    = (const float*)d_in[13];
  const float* scb1    = (const float*)d_in[14];
  const float* scW2    = (const float*)d_in[15];
  const float* scb2    = (const float*)d_in[16];
  const int* num_atoms = (const int*)d_in[17];
  const int* atype     = (const int*)d_in[18];
  const int* batch     = (const int*)d_in[19];
  const int* ei        = (const int*)d_in[20];
  const int* toj       = (const int*)d_in[21];
  const int* tsteps    = (const int*)d_in[22];
  float* ws = (float*)d_ws;
  float* out = (float*)d_out;
  unsigned short* w0t = (unsigned short*)(ws + WS_W0T_F);
  unsigned short* w1t = (unsigned short*)(ws + WS_W1T_F);

  hipLaunchKernelGGL(k_init, dim3(256), dim3(256), 0, stream, ws);
  hipLaunchKernelGGL(k_lattice, dim3(1), dim3(128), 0, stream, lengths, angles, sigmas, tsteps, ws);
  hipLaunchKernelGGL(k_hb, dim3(100), dim3(128), 0, stream, aemb, bbW, ws);
  hipLaunchKernelGGL(k_rbfw2, dim3(1), dim3(128), 0, stream, rbfW, rbfb, bbW, bbb, ws);
  hipLaunchKernelGGL(k_latproj, dim3(128), dim3(256), 0, stream, latents, scW0, scb0, ws);
  hipLaunchKernelGGL(k_node, dim3(50), dim3(256), 0, stream, gtf, noise, batch, ws);
  hipLaunchKernelGGL(k_cvtW0, dim3(256), dim3(256), 0, stream, scW0, w0t);
  hipLaunchKernelGGL(k_cvtW1, dim3(1024), dim3(256), 0, stream, scW1, w1t);
  hipLaunchKernelGGL(k_edge, dim3(Ee / TE), dim3(256), 0, stream,
                     ei, toj, batch, atype, w0t, w1t, scb1, scW2, scb2, ws);
  hipLaunchKernelGGL(k_node2, dim3(50), dim3(256), 0, stream, batch, ws);
  hipLaunchKernelGGL(k_minmax, dim3(50), dim3(256), 0, stream, batch, num_atoms, ws);
  hipLaunchKernelGGL(k_final, dim3(1), dim3(128), 0, stream, num_atoms, ws, out);
}

// Round 4
// 538.036 us; speedup vs baseline: 5.2103x; 1.0301x over previous
//
#include <hip/hip_runtime.h>
#include <hip/hip_bf16.h>

// ---------------- problem constants ----------------
namespace {
constexpr int Bb = 128, Nn = 12800, Ee = 262144;
constexpr int LAT = 256, HID = 128, FCH = 512, NRBF = 16;
constexpr int TE = 64; // edges per block in edge kernel (divides 2048 = edges/graph)

// workspace offsets (floats)
constexpr int WS_L      = 0;        // B*9
constexpr int WS_LI     = 1152;     // B*9
constexpr int WS_SIG    = 2304;     // B
constexpr int WS_RBFW2  = 2432;     // 16*128
constexpr int WS_CVEC   = 4480;     // 128
constexpr int WS_HB     = 4608;     // 100*128
constexpr int WS_LATP   = 17408;    // B*512
constexpr int WS_PERT   = 82944;    // N*3
constexpr int WS_ALIGN  = 121344;   // N*3
constexpr int WS_SN     = 159744;   // N*3 (atomic)
constexpr int WS_GN     = 198144;   // N*3 (atomic)
constexpr int WS_PREDS  = 236544;   // N*3
constexpr int WS_BSUM   = 274944;   // B*3 (atomic)
constexpr int WS_CENTER = 275328;   // B*3 (atomic)
constexpr int WS_MINMAX = 275712;   // 6   (max x3, min x3)
// bf16 fragment-tiled weights (stored as ushort), float-index base:
constexpr int WS_W0T_F  = 276000;   // ushort[512*128]  (= 32768 floats)
constexpr int WS_W1T_F  = 308768;   // ushort[512*512]  (= 131072 floats)
}

typedef short bf16x8 __attribute__((ext_vector_type(8)));
typedef unsigned short u16x8 __attribute__((ext_vector_type(8)));
typedef float f32x4 __attribute__((ext_vector_type(4)));

static __device__ __forceinline__ unsigned short f2bf(float f) {
  unsigned int u = __float_as_uint(f);
  unsigned int r = (u + 0x7fffu + ((u >> 16) & 1u)) >> 16;
  return (unsigned short)r;
}

static __device__ __forceinline__ void atomicMaxFloat(float* addr, float val) {
  int* ai = reinterpret_cast<int*>(addr);
  int old = *ai;
  while (__int_as_float(old) < val) {
    int assumed = old;
    old = atomicCAS(ai, assumed, __float_as_int(val));
    if (old == assumed) break;
  }
}
static __device__ __forceinline__ void atomicMinFloat(float* addr, float val) {
  int* ai = reinterpret_cast<int*>(addr);
  int old = *ai;
  while (__int_as_float(old) > val) {
    int assumed = old;
    old = atomicCAS(ai, assumed, __float_as_int(val));
    if (old == assumed) break;
  }
}

// ---------------- fused prologue: all mutually-independent prep work ----------------
// blocks   0..303 : zero SN/GN/BSUM/CENTER, init MINMAX
// block      304  : lattice + sigma
// blocks 305..404 : hb = atom_emb @ bb_W     (tile = b-305)
// block      405  : rbfW2 / cvec
// blocks 406..533 : lat_proj                  (graph = b-406)
// blocks 534..789 : cvtW0
// blocks 790..1813: cvtW1
__global__ __launch_bounds__(256) void k_pre(
    const float* lengths, const float* angles, const float* sigmas, const int* tsteps,
    const float* aemb, const float* bbW, const float* rbfW, const float* rbfb,
    const float* bbb, const float* latents, const float* scW0, const float* scb0,
    const float* scW1, unsigned short* w0t, unsigned short* w1t, float* ws) {
  const int blk = blockIdx.x, t = threadIdx.x;
  if (blk < 304) {
    int gid = blk * 256 + t;
    if (gid < 2 * Nn * 3) ws[WS_SN + gid] = 0.f;
    else if (gid < 2 * Nn * 3 + 2 * Bb * 3) ws[WS_BSUM + (gid - 2 * Nn * 3)] = 0.f;
    else if (gid < 2 * Nn * 3 + 2 * Bb * 3 + 3) ws[WS_MINMAX + (gid - 2 * Nn * 3 - 2 * Bb * 3)] = -3.0e38f;
    else if (gid < 2 * Nn * 3 + 2 * Bb * 3 + 6) ws[WS_MINMAX + (gid - 2 * Nn * 3 - 2 * Bb * 3)] = 3.0e38f;
  } else if (blk == 304) {
    int b = t;
    if (b >= Bb) return;
    float a = lengths[b * 3 + 0], bl = lengths[b * 3 + 1], c = lengths[b * 3 + 2];
    const float d2r = 0.017453292519943295f;
    float al = angles[b * 3 + 0] * d2r, be = angles[b * 3 + 1] * d2r, ga = angles[b * 3 + 2] * d2r;
    float ca = cosf(al), cb = cosf(be), cg = cosf(ga), sa = sinf(al), sb = sinf(be);
    float val = (ca * cb - cg) / (sa * sb);
    val = fminf(1.f, fmaxf(-1.f, val));
    float gs = acosf(val);
    float L[3][3];
    L[0][0] = a * sb;              L[0][1] = 0.f;                L[0][2] = a * cb;
    L[1][0] = -bl * sa * cosf(gs); L[1][1] = bl * sa * sinf(gs); L[1][2] = bl * ca;
    L[2][0] = 0.f;                 L[2][1] = 0.f;                L[2][2] = c;
    float det = L[0][0] * (L[1][1] * L[2][2] - L[1][2] * L[2][1])
              - L[0][1] * (L[1][0] * L[2][2] - L[1][2] * L[2][0])
              + L[0][2] * (L[1][0] * L[2][1] - L[1][1] * L[2][0]);
    float id = 1.f / det;
    float inv[3][3];
    inv[0][0] =  (L[1][1]*L[2][2] - L[1][2]*L[2][1]) * id;
    inv[0][1] = -(L[0][1]*L[2][2] - L[0][2]*L[2][1]) * id;
    inv[0][2] =  (L[0][1]*L[1][2] - L[0][2]*L[1][1]) * id;
    inv[1][0] = -(L[1][0]*L[2][2] - L[1][2]*L[2][0]) * id;
    inv[1][1] =  (L[0][0]*L[2][2] - L[0][2]*L[2][0]) * id;
    inv[1][2] = -(L[0][0]*L[1][2] - L[0][2]*L[1][0]) * id;
    inv[2][0] =  (L[1][0]*L[2][1] - L[1][1]*L[2][0]) * id;
    inv[2][1] = -(L[0][0]*L[2][1] - L[0][1]*L[2][0]) * id;
    inv[2][2] =  (L[0][0]*L[1][1] - L[0][1]*L[1][0]) * id;
    for (int i = 0; i < 3; ++i)
      for (int j = 0; j < 3; ++j) {
        ws[WS_L + b * 9 + i * 3 + j] = L[i][j];
        ws[WS_LI + b * 9 + i * 3 + j] = inv[i][j];
      }
    ws[WS_SIG + b] = sigmas[tsteps[b]];
  } else if (blk < 405) {
    int tile = blk - 305;
    if (t < HID) {
      float acc = 0.f;
      for (int k = 0; k < HID; ++k) acc += aemb[tile * HID + k] * bbW[k * HID + t];
      ws[WS_HB + tile * HID + t] = acc;
    }
  } else if (blk == 405) {
    if (t < HID) {
      float accs[NRBF];
#pragma unroll
      for (int k = 0; k < NRBF; ++k) accs[k] = 0.f;
      float accb = 0.f;
      for (int m = 0; m < HID; ++m) {
        float w = bbW[m * HID + t];
#pragma unroll
        for (int k = 0; k < NRBF; ++k) accs[k] += rbfW[k * HID + m] * w;
        accb += rbfb[m] * w;
      }
#pragma unroll
      for (int k = 0; k < NRBF; ++k) ws[WS_RBFW2 + k * HID + t] = accs[k];
      ws[WS_CVEC + t] = accb + bbb[t];
    }
  } else if (blk < 534) {
    int b = blk - 406;
    __shared__ float lat[LAT];
    lat[t] = latents[b * LAT + t];
    __syncthreads();
    int c0 = 2 * t;
    float a0 = 0.f, a1 = 0.f;
    for (int m = 0; m < LAT; ++m) {
      float2 w = *reinterpret_cast<const float2*>(scW0 + (HID + m) * FCH + c0);
      float lm = lat[m];
      a0 += lm * w.x;
      a1 += lm * w.y;
    }
    ws[WS_LATP + b * FCH + c0] = a0 + scb0[c0];
    ws[WS_LATP + b * FCH + c0 + 1] = a1 + scb0[c0 + 1];
  } else if (blk < 790) {
    int id = (blk - 534) * 256 + t;   // 65536
    int e = id & 7, lane = (id >> 3) & 63, tile = id >> 9;  // tile = colTile*4 + kTile
    int colTile = tile >> 2, kTile = tile & 3;
    int col = colTile * 16 + (lane & 15);
    int k = kTile * 32 + (lane >> 4) * 8 + e;
    w0t[id] = f2bf(scW0[k * FCH + col]);
  } else {
    int id = (blk - 790) * 256 + t;   // 262144
    int e = id & 7, lane = (id >> 3) & 63, tile = id >> 9;  // tile = colTile*16 + kTile
    int colTile = tile >> 4, kTile = tile & 15;
    int col = colTile * 16 + (lane & 15);
    int k = kTile * 32 + (lane >> 4) * 8 + e;
    w1t[id] = f2bf(scW1[k * FCH + col]);
  }
}

// ---------------- per-node geometry ----------------
__global__ void k_node(const float* frac, const float* noise, const int* batch, float* ws) {
  int n = blockIdx.x * blockDim.x + threadIdx.x;
  if (n >= Nn) return;
  int b = batch[n];
  float L[9], Li[9];
#pragma unroll
  for (int i = 0; i < 9; ++i) { L[i] = ws[WS_L + b * 9 + i]; Li[i] = ws[WS_LI + b * 9 + i]; }
  float f0 = frac[n * 3], f1 = frac[n * 3 + 1], f2 = frac[n * 3 + 2];
  float cg[3], p0[3], fp[3], pe[3], fg[3], fd[3];
#pragma unroll
  for (int j = 0; j < 3; ++j) cg[j] = f0 * L[j] + f1 * L[3 + j] + f2 * L[6 + j];
  float sig = ws[WS_SIG + b];
#pragma unroll
  for (int j = 0; j < 3; ++j) p0[j] = cg[j] + sig * noise[n * 3 + j];
#pragma unroll
  for (int j = 0; j < 3; ++j) {
    float v = p0[0] * Li[j] + p0[1] * Li[3 + j] + p0[2] * Li[6 + j];
    fp[j] = v - floorf(v);
  }
#pragma unroll
  for (int j = 0; j < 3; ++j) pe[j] = fp[0] * L[j] + fp[1] * L[3 + j] + fp[2] * L[6 + j];
#pragma unroll
  for (int j = 0; j < 3; ++j) fg[j] = cg[0] * Li[j] + cg[1] * Li[3 + j] + cg[2] * Li[6 + j];
#pragma unroll
  for (int j = 0; j < 3; ++j) { float d = fg[j] - fp[j]; fd[j] = d - rintf(d); }
#pragma unroll
  for (int j = 0; j < 3; ++j) {
    ws[WS_PERT + n * 3 + j] = pe[j];
    ws[WS_ALIGN + n * 3 + j] = pe[j] + fd[0] * L[j] + fd[1] * L[3 + j] + fd[2] * L[6 + j];
  }
}

// ---------------- the big fused MFMA edge kernel ----------------
// Tile: 64 edges x 512 cols. 8 waves; wave w owns cols [w*64, w*64+64)
// (4 col-tiles) across all 4 edge m-tiles.
// mfma_f32_16x16x32_bf16: A-frag lane l holds A[l&15][8*(l>>4)+e];
// B-frag lane l holds B[8*(l>>4)+e][l&15]; D: col=l&15, row=(l>>4)*4+r.
__global__ __launch_bounds__(512, 2) void k_edge(
    const int* ei, const int* toj, const int* batch, const int* atype,
    const unsigned short* w0t, const unsigned short* w1t,
    const float* scb1, const float* scW2, const float* scb2, float* ws) {
  __shared__ unsigned short s_ef[TE * HID];   // 16 KB, XOR-swizzled rows (256B)
  __shared__ unsigned short s_hh[TE * FCH];   // 64 KB, XOR-swizzled rows (1024B)
  __shared__ float s_latp[FCH];               // 2 KB
  __shared__ float s_rbf[TE][NRBF];           // 4 KB
  __shared__ float s_dvec[TE][3];
  __shared__ float s_dist[TE], s_gtd[TE];
  __shared__ int s_tj[TE], s_ti[TE];
  __shared__ float s_wsum[8][TE];             // 2 KB

  char* s_ef_b = (char*)s_ef;
  char* s_hh_b = (char*)s_hh;
  const int t = threadIdx.x;
  const int e0 = blockIdx.x * TE;

  // ---- Phase A: latp staging (tile lies within one graph) + per-edge geometry
  int b0 = batch[ei[e0]];
  if (t < 128) {
    ((float4*)s_latp)[t] = ((const float4*)(ws + WS_LATP + b0 * FCH))[t];
  }
  if (t < TE) {
    int e = e0 + t;
    int jn = ei[e], iN = ei[Ee + e];
    int b = batch[jn];
    float tx = (float)toj[e * 3], ty = (float)toj[e * 3 + 1], tz = (float)toj[e * 3 + 2];
    const float* L = ws + WS_L + b * 9;
    float dv[3], gv[3];
#pragma unroll
    for (int j = 0; j < 3; ++j) {
      float off = tx * L[j] + ty * L[3 + j] + tz * L[6 + j];
      dv[j] = ws[WS_PERT + iN * 3 + j] - ws[WS_PERT + jn * 3 + j] - off;
      gv[j] = ws[WS_ALIGN + iN * 3 + j] - ws[WS_ALIGN + jn * 3 + j] - off;
    }
    float dist = sqrtf(dv[0] * dv[0] + dv[1] * dv[1] + dv[2] * dv[2]);
    float gtd = sqrtf(gv[0] * gv[0] + gv[1] * gv[1] + gv[2] * gv[2]);
#pragma unroll
    for (int j = 0; j < 3; ++j) s_dvec[t][j] = dv[j];
    s_dist[t] = dist;
    s_gtd[t] = gtd;
    s_tj[t] = atype[jn]; s_ti[t] = atype[iN];
    const float step = 7.0f / 15.0f;
#pragma unroll
    for (int k = 0; k < NRBF; ++k) {
      float d = dist - (float)k * step;
      s_rbf[t][k] = expf(-10.f * d * d);
    }
  }
  __syncthreads();

  // ---- Phase B: ef = silu(hb[tj]+hb[ti]+rbf@rbfW2+cvec) -> bf16 LDS (swizzled)
  {
    int e = t >> 3;              // 0..63
    int c0 = (t & 7) * 16;       // 16 cols per thread
    int tj = s_tj[e], ti = s_ti[e];
    float4 z4[4];
#pragma unroll
    for (int q = 0; q < 4; ++q) {
      float4 a = *(const float4*)(ws + WS_HB + tj * HID + c0 + q * 4);
      float4 bq = *(const float4*)(ws + WS_HB + ti * HID + c0 + q * 4);
      float4 cv = *(const float4*)(ws + WS_CVEC + c0 + q * 4);
      z4[q].x = a.x + bq.x + cv.x; z4[q].y = a.y + bq.y + cv.y;
      z4[q].z = a.z + bq.z + cv.z; z4[q].w = a.w + bq.w + cv.w;
    }
#pragma unroll
    for (int k = 0; k < NRBF; ++k) {
      float rbk = s_rbf[e][k];
#pragma unroll
      for (int q = 0; q < 4; ++q) {
        float4 wv4 = *(const float4*)(ws + WS_RBFW2 + k * HID + c0 + q * 4);
        z4[q].x += rbk * wv4.x; z4[q].y += rbk * wv4.y;
        z4[q].z += rbk * wv4.z; z4[q].w += rbk * wv4.w;
      }
    }
    u16x8 o0, o1;
#pragma unroll
    for (int q = 0; q < 4; ++q) {
      float zz[4] = {z4[q].x, z4[q].y, z4[q].z, z4[q].w};
#pragma unroll
      for (int j = 0; j < 4; ++j) {
        float z = zz[j];
        float sv = z / (1.f + expf(-z));
        unsigned short us = f2bf(sv);
        if (q < 2) o0[q * 4 + j] = us; else o1[(q - 2) * 4 + j] = us;
      }
    }
    int base = e * 256 + c0 * 2;
    int sw = (e & 7) << 4;
    *(u16x8*)(s_ef_b + ((base) ^ sw)) = o0;
    *(u16x8*)(s_ef_b + ((base + 16) ^ sw)) = o1;
  }
  __syncthreads();

  const int lane = t & 63;
  const int wv = t >> 6;        // 0..7
  const int lr = lane & 15;     // col (D) / row (A) index
  const int lq = lane >> 4;     // k-quadrant

  // ---- Phase C: GEMM1  hh = relu(ef @ W0a + latp), bf16 -> LDS (swizzled)
  {
    f32x4 acc[4][4];
#pragma unroll
    for (int m = 0; m < 4; ++m)
#pragma unroll
      for (int n = 0; n < 4; ++n) acc[m][n] = (f32x4){0.f, 0.f, 0.f, 0.f};
    const unsigned short* w0l = w0t + lane * 8;
    // preload ALL W0 fragments for this wave (16 frags)
    bf16x8 bw[4][4];
#pragma unroll
    for (int kt = 0; kt < 4; ++kt)
#pragma unroll
      for (int n = 0; n < 4; ++n)
        bw[kt][n] = *(const bf16x8*)(w0l + (size_t)((wv * 4 + n) * 4 + kt) * 512);
#pragma unroll
    for (int kt = 0; kt < 4; ++kt) {
      bf16x8 a[4];
#pragma unroll
      for (int m = 0; m < 4; ++m) {
        int row = m * 16 + lr;
        int off = (row * 256 + (kt * 32 + lq * 8) * 2) ^ ((row & 7) << 4);
        a[m] = *(const bf16x8*)(s_ef_b + off);
      }
#pragma unroll
      for (int n = 0; n < 4; ++n)
#pragma unroll
        for (int m = 0; m < 4; ++m)
          acc[m][n] = __builtin_amdgcn_mfma_f32_16x16x32_bf16(a[m], bw[kt][n], acc[m][n], 0, 0, 0);
    }
#pragma unroll
    for (int m = 0; m < 4; ++m)
#pragma unroll
      for (int n = 0; n < 4; ++n) {
        int col = wv * 64 + n * 16 + lr;
        float lp = s_latp[col];
        f32x4 v = acc[m][n];
#pragma unroll
        for (int r = 0; r < 4; ++r) {
          int row = m * 16 + lq * 4 + r;
          float h = fmaxf(v[r] + lp, 0.f);
          int off = (row * 1024 + col * 2) ^ ((row & 7) << 4);
          *(unsigned short*)(s_hh_b + off) = f2bf(h);
        }
      }
  }
  __syncthreads();

  // ---- Phase D: GEMM2 + fused score reduction (1-deep B prefetch pipeline)
  {
    f32x4 acc[4][4];
#pragma unroll
    for (int m = 0; m < 4; ++m)
#pragma unroll
      for (int n = 0; n < 4; ++n) acc[m][n] = (f32x4){0.f, 0.f, 0.f, 0.f};
    const unsigned short* w1l = w1t + lane * 8;
    bf16x8 breg[2][4];
#pragma unroll
    for (int n = 0; n < 4; ++n)
      breg[0][n] = *(const bf16x8*)(w1l + (size_t)((wv * 4 + n) * 16 + 0) * 512);
#pragma unroll
    for (int kt = 0; kt < 16; ++kt) {
      const int cur = kt & 1;
      if (kt < 15) {
#pragma unroll
        for (int n = 0; n < 4; ++n)
          breg[cur ^ 1][n] = *(const bf16x8*)(w1l + (size_t)((wv * 4 + n) * 16 + kt + 1) * 512);
      }
      bf16x8 a[4];
#pragma unroll
      for (int m = 0; m < 4; ++m) {
        int row = m * 16 + lr;
        int off = (row * 1024 + (kt * 32 + lq * 8) * 2) ^ ((row & 7) << 4);
        a[m] = *(const bf16x8*)(s_hh_b + off);
      }
#pragma unroll
      for (int n = 0; n < 4; ++n)
#pragma unroll
        for (int m = 0; m < 4; ++m)
          acc[m][n] = __builtin_amdgcn_mfma_f32_16x16x32_bf16(a[m], breg[cur][n], acc[m][n], 0, 0, 0);
    }
    // hh1 = relu(acc + b1); p += hh1 * W2   (per lane: 4 cols x 16 rows)
    float p[4][4];
#pragma unroll
    for (int m = 0; m < 4; ++m)
#pragma unroll
      for (int r = 0; r < 4; ++r) p[m][r] = 0.f;
#pragma unroll
    for (int n = 0; n < 4; ++n) {
      int col = wv * 64 + n * 16 + lr;
      float b1v = scb1[col];
      float w2v = scW2[col];
#pragma unroll
      for (int m = 0; m < 4; ++m) {
        f32x4 v = acc[m][n];
#pragma unroll
        for (int r = 0; r < 4; ++r) p[m][r] += fmaxf(v[r] + b1v, 0.f) * w2v;
      }
    }
    // reduce over the 16 lanes sharing a row (lane bits 0..3)
#pragma unroll
    for (int m = 0; m < 4; ++m)
#pragma unroll
      for (int r = 0; r < 4; ++r) {
        float x = p[m][r];
        x += __shfl_xor(x, 1);
        x += __shfl_xor(x, 2);
        x += __shfl_xor(x, 4);
        x += __shfl_xor(x, 8);
        p[m][r] = x;
      }
    if (lr == 0) {
#pragma unroll
      for (int m = 0; m < 4; ++m)
#pragma unroll
        for (int r = 0; r < 4; ++r) s_wsum[wv][m * 16 + lq * 4 + r] = p[m][r];
    }
  }
  __syncthreads();

  // ---- Phase E: segment-mean scatter (threads 0..63)
  if (t < TE) {
    int e = e0 + t;
    float score = scb2[0];
#pragma unroll
    for (int w = 0; w < 8; ++w) score += s_wsum[w][t];
    int jn = ei[e], iN = ei[Ee + e];
    int s = e;
    while (s > 0 && ei[s - 1] == jn && ei[Ee + s - 1] == iN) --s;
    int en = e;
    while (en + 1 < Ee && ei[en + 1] == jn && ei[Ee + en + 1] == iN) ++en;
    float invc = 1.f / (float)(en - s + 1);
    float dist = s_dist[t];
    float denom = dist + 1e-8f;
    float gts = s_gtd[t] - dist;
#pragma unroll
    for (int j = 0; j < 3; ++j) {
      float dir = s_dvec[t][j] / denom;
      atomicAdd(&ws[WS_SN + iN * 3 + j], score * dir * invc);
      atomicAdd(&ws[WS_GN + iN * 3 + j], gts * dir * invc);
    }
  }
}

// ---------------- per-node: loss terms, preds, center sums ----------------
__global__ void k_node2(const int* batch, float* ws) {
  int n = blockIdx.x * blockDim.x + threadIdx.x;
  if (n >= Nn) return;
  int b = batch[n];
  float sig = ws[WS_SIG + b];
#pragma unroll
  for (int j = 0; j < 3; ++j) {
    float s = ws[WS_SN + n * 3 + j], g = ws[WS_GN + n * 3 + j];
    float d = s - g / sig;
    atomicAdd(&ws[WS_BSUM + b * 3 + j], d * d);
    float pr = ws[WS_PERT + n * 3 + j] + s / sig;
    ws[WS_PREDS + n * 3 + j] = pr;
    atomicAdd(&ws[WS_CENTER + b * 3 + j], pr);
  }
}

// ---------------- per-node: global min/max of dc ----------------
__global__ void k_minmax(const int* batch, const int* num_atoms, float* ws) {
  int n = blockIdx.x * blockDim.x + threadIdx.x;
  int lane = threadIdx.x & 63, wid = threadIdx.x >> 6;
  float mx[3], mn[3];
  if (n < Nn) {
    int b = batch[n];
    float na = (float)num_atoms[b];
#pragma unroll
    for (int j = 0; j < 3; ++j) {
      float v = ws[WS_PREDS + n * 3 + j] - ws[WS_CENTER + b * 3 + j] / na;
      mx[j] = v; mn[j] = v;
    }
  } else {
#pragma unroll
    for (int j = 0; j < 3; ++j) { mx[j] = -3.0e38f; mn[j] = 3.0e38f; }
  }
#pragma unroll
  for (int off = 32; off >= 1; off >>= 1) {
#pragma unroll
    for (int j = 0; j < 3; ++j) {
      mx[j] = fmaxf(mx[j], __shfl_xor(mx[j], off));
      mn[j] = fminf(mn[j], __shfl_xor(mn[j], off));
    }
  }
  __shared__ float smx[4][3], smn[4][3];
  if (lane == 0) {
#pragma unroll
    for (int j = 0; j < 3; ++j) { smx[wid][j] = mx[j]; smn[wid][j] = mn[j]; }
  }
  __syncthreads();
  if (threadIdx.x == 0) {
#pragma unroll
    for (int j = 0; j < 3; ++j) {
      float M = fmaxf(fmaxf(smx[0][j], smx[1][j]), fmaxf(smx[2][j], smx[3][j]));
      float m = fminf(fminf(smn[0][j], smn[1][j]), fminf(smn[2][j], smn[3][j]));
      atomicMaxFloat(&ws[WS_MINMAX + j], M);
      atomicMinFloat(&ws[WS_MINMAX + 3 + j], m);
    }
  }
}

// ---------------- finalize (parallel over batches) ----------------
__global__ void k_final(const int* num_atoms, const float* ws, float* out) {
  int t = threadIdx.x;  // 128 threads
  float loss = 0.f;
  if (t < Bb) {
    float na = (float)num_atoms[t];
    loss = (ws[WS_BSUM + t * 3] + ws[WS_BSUM + t * 3 + 1] + ws[WS_BSUM + t * 3 + 2]) / na;
  }
#pragma unroll
  for (int off = 32; off >= 1; off >>= 1) loss += __shfl_xor(loss, off);
  __shared__ float s2[2];
  if ((t & 63) == 0) s2[t >> 6] = loss;
  __syncthreads();
  if (t == 0) {
    float L = (s2[0] + s2[1]) / (3.0f * (float)Bb);
    float pbs = fabsf(ws[WS_MINMAX + 0] + ws[WS_MINMAX + 3]) +
                fabsf(ws[WS_MINMAX + 1] + ws[WS_MINMAX + 4]) +
                fabsf(ws[WS_MINMAX + 2] + ws[WS_MINMAX + 5]);
    out[0] = L;
    out[1] = pbs;
  }
}

extern "C" void kernel_launch(void* const* d_in, const int* in_sizes, int n_in,
                              void* d_out, int out_size, void* d_ws, size_t ws_size,
                              hipStream_t stream) {
  const float* latents = (const float*)d_in[0];
  const float* gtf     = (const float*)d_in[1];
  const float* lengths = (const float*)d_in[2];
  const float* angles  = (const float*)d_in[3];
  const float* noise   = (const float*)d_in[4];
  const float* sigmas  = (const float*)d_in[5];
  const float* aemb    = (const float*)d_in[6];
  const float* rbfW    = (const float*)d_in[7];
  const float* rbfb    = (const float*)d_in[8];
  const float* bbW     = (const float*)d_in[9];
  const float* bbb     = (const float*)d_in[10];
  const float* scW0    = (const float*)d_in[11];
  const float* scb0    = (const float*)d_in[12];
  const float* scW1    = (const float*)d_in[13];
  const float* scb1    = (const float*)d_in[14];
  const float* scW2    = (const float*)d_in[15];
  const float* scb2    = (const float*)d_in[16];
  const int* num_atoms = (const int*)d_in[17];
  const int* atype     = (const int*)d_in[18];
  const int* batch     = (const int*)d_in[19];
  const int* ei        = (const int*)d_in[20];
  const int* toj       = (const int*)d_in[21];
  const int* tsteps    = (const int*)d_in[22];
  float* ws = (float*)d_ws;
  float* out = (float*)d_out;
  unsigned short* w0t = (unsigned short*)(ws + WS_W0T_F);
  unsigned short* w1t = (unsigned short*)(ws + WS_W1T_F);

  hipLaunchKernelGGL(k_pre, dim3(1814), dim3(256), 0, stream,
                     lengths, angles, sigmas, tsteps, aemb, bbW, rbfW, rbfb, bbb,
                     latents, scW0, scb0, scW1, w0t, w1t, ws);
  hipLaunchKernelGGL(k_node, dim3(50), dim3(256), 0, stream, gtf, noise, batch, ws);
  hipLaunchKernelGGL(k_edge, dim3(Ee / TE), dim3(512), 0, stream,
                     ei, toj, batch, atype, w0t, w1t, scb1, scW2, scb2, ws);
  hipLaunchKernelGGL(k_node2, dim3(50), dim3(256), 0, stream, batch, ws);
  hipLaunchKernelGGL(k_minmax, dim3(50), dim3(256), 0, stream, batch, num_atoms, ws);
  hipLaunchKernelGGL(k_final, dim3(1), dim3(128), 0, stream, num_atoms, ws, out);
}

// Round 5
// 505.867 us; speedup vs baseline: 5.5416x; 1.0636x over previous
//
#include <hip/hip_runtime.h>
#include <hip/hip_bf16.h>

// ---------------- problem constants ----------------
namespace {
constexpr int Bb = 128, Nn = 12800, Ee = 262144;
constexpr int LAT = 256, HID = 128, FCH = 512, NRBF = 16;
constexpr int TE = 64; // edges per block in edge kernel (divides 2048 = edges/graph)

// workspace offsets (floats)
constexpr int WS_L      = 0;        // B*9
constexpr int WS_LI     = 1152;     // B*9
constexpr int WS_SIG    = 2304;     // B
constexpr int WS_RBFW2  = 2432;     // 16*128
constexpr int WS_CVEC   = 4480;     // 128
constexpr int WS_HB     = 4608;     // 100*128
constexpr int WS_LATP   = 17408;    // B*512
constexpr int WS_PERT   = 82944;    // N*3
constexpr int WS_ALIGN  = 121344;   // N*3
constexpr int WS_SN     = 159744;   // N*3 (atomic)
constexpr int WS_GN     = 198144;   // N*3 (atomic)
constexpr int WS_PREDS  = 236544;   // N*3
constexpr int WS_BSUM   = 274944;   // B*3 (atomic)
constexpr int WS_CENTER = 275328;   // B*3 (atomic)
constexpr int WS_MINMAX = 275712;   // 6   (max x3, min x3)
// bf16 fragment-tiled weights (stored as ushort), float-index base:
constexpr int WS_W0T_F  = 276000;   // ushort[512*128]  (= 32768 floats)
constexpr int WS_W1T_F  = 308768;   // ushort[512*512]  (= 131072 floats)
}

typedef short bf16x8 __attribute__((ext_vector_type(8)));
typedef unsigned short u16x8 __attribute__((ext_vector_type(8)));
typedef float f32x4 __attribute__((ext_vector_type(4)));

static __device__ __forceinline__ unsigned short f2bf(float f) {
  unsigned int u = __float_as_uint(f);
  unsigned int r = (u + 0x7fffu + ((u >> 16) & 1u)) >> 16;
  return (unsigned short)r;
}

static __device__ __forceinline__ void atomicMaxFloat(float* addr, float val) {
  int* ai = reinterpret_cast<int*>(addr);
  int old = *ai;
  while (__int_as_float(old) < val) {
    int assumed = old;
    old = atomicCAS(ai, assumed, __float_as_int(val));
    if (old == assumed) break;
  }
}
static __device__ __forceinline__ void atomicMinFloat(float* addr, float val) {
  int* ai = reinterpret_cast<int*>(addr);
  int old = *ai;
  while (__int_as_float(old) > val) {
    int assumed = old;
    old = atomicCAS(ai, assumed, __float_as_int(val));
    if (old == assumed) break;
  }
}

// ---------------- fused prologue: all mutually-independent prep work ----------------
__global__ __launch_bounds__(256) void k_pre(
    const float* lengths, const float* angles, const float* sigmas, const int* tsteps,
    const float* aemb, const float* bbW, const float* rbfW, const float* rbfb,
    const float* bbb, const float* latents, const float* scW0, const float* scb0,
    const float* scW1, unsigned short* w0t, unsigned short* w1t, float* ws) {
  const int blk = blockIdx.x, t = threadIdx.x;
  if (blk < 304) {
    int gid = blk * 256 + t;
    if (gid < 2 * Nn * 3) ws[WS_SN + gid] = 0.f;
    else if (gid < 2 * Nn * 3 + 2 * Bb * 3) ws[WS_BSUM + (gid - 2 * Nn * 3)] = 0.f;
    else if (gid < 2 * Nn * 3 + 2 * Bb * 3 + 3) ws[WS_MINMAX + (gid - 2 * Nn * 3 - 2 * Bb * 3)] = -3.0e38f;
    else if (gid < 2 * Nn * 3 + 2 * Bb * 3 + 6) ws[WS_MINMAX + (gid - 2 * Nn * 3 - 2 * Bb * 3)] = 3.0e38f;
  } else if (blk == 304) {
    int b = t;
    if (b >= Bb) return;
    float a = lengths[b * 3 + 0], bl = lengths[b * 3 + 1], c = lengths[b * 3 + 2];
    const float d2r = 0.017453292519943295f;
    float al = angles[b * 3 + 0] * d2r, be = angles[b * 3 + 1] * d2r, ga = angles[b * 3 + 2] * d2r;
    float ca = cosf(al), cb = cosf(be), cg = cosf(ga), sa = sinf(al), sb = sinf(be);
    float val = (ca * cb - cg) / (sa * sb);
    val = fminf(1.f, fmaxf(-1.f, val));
    float gs = acosf(val);
    float L[3][3];
    L[0][0] = a * sb;              L[0][1] = 0.f;                L[0][2] = a * cb;
    L[1][0] = -bl * sa * cosf(gs); L[1][1] = bl * sa * sinf(gs); L[1][2] = bl * ca;
    L[2][0] = 0.f;                 L[2][1] = 0.f;                L[2][2] = c;
    float det = L[0][0] * (L[1][1] * L[2][2] - L[1][2] * L[2][1])
              - L[0][1] * (L[1][0] * L[2][2] - L[1][2] * L[2][0])
              + L[0][2] * (L[1][0] * L[2][1] - L[1][1] * L[2][0]);
    float id = 1.f / det;
    float inv[3][3];
    inv[0][0] =  (L[1][1]*L[2][2] - L[1][2]*L[2][1]) * id;
    inv[0][1] = -(L[0][1]*L[2][2] - L[0][2]*L[2][1]) * id;
    inv[0][2] =  (L[0][1]*L[1][2] - L[0][2]*L[1][1]) * id;
    inv[1][0] = -(L[1][0]*L[2][2] - L[1][2]*L[2][0]) * id;
    inv[1][1] =  (L[0][0]*L[2][2] - L[0][2]*L[2][0]) * id;
    inv[1][2] = -(L[0][0]*L[1][2] - L[0][2]*L[1][0]) * id;
    inv[2][0] =  (L[1][0]*L[2][1] - L[1][1]*L[2][0]) * id;
    inv[2][1] = -(L[0][0]*L[2][1] - L[0][1]*L[2][0]) * id;
    inv[2][2] =  (L[0][0]*L[1][1] - L[0][1]*L[1][0]) * id;
    for (int i = 0; i < 3; ++i)
      for (int j = 0; j < 3; ++j) {
        ws[WS_L + b * 9 + i * 3 + j] = L[i][j];
        ws[WS_LI + b * 9 + i * 3 + j] = inv[i][j];
      }
    ws[WS_SIG + b] = sigmas[tsteps[b]];
  } else if (blk < 405) {
    int tile = blk - 305;
    if (t < HID) {
      float acc = 0.f;
      for (int k = 0; k < HID; ++k) acc += aemb[tile * HID + k] * bbW[k * HID + t];
      ws[WS_HB + tile * HID + t] = acc;
    }
  } else if (blk == 405) {
    if (t < HID) {
      float accs[NRBF];
#pragma unroll
      for (int k = 0; k < NRBF; ++k) accs[k] = 0.f;
      float accb = 0.f;
      for (int m = 0; m < HID; ++m) {
        float w = bbW[m * HID + t];
#pragma unroll
        for (int k = 0; k < NRBF; ++k) accs[k] += rbfW[k * HID + m] * w;
        accb += rbfb[m] * w;
      }
#pragma unroll
      for (int k = 0; k < NRBF; ++k) ws[WS_RBFW2 + k * HID + t] = accs[k];
      ws[WS_CVEC + t] = accb + bbb[t];
    }
  } else if (blk < 534) {
    int b = blk - 406;
    __shared__ float lat[LAT];
    lat[t] = latents[b * LAT + t];
    __syncthreads();
    int c0 = 2 * t;
    float a0 = 0.f, a1 = 0.f;
    for (int m = 0; m < LAT; ++m) {
      float2 w = *reinterpret_cast<const float2*>(scW0 + (HID + m) * FCH + c0);
      float lm = lat[m];
      a0 += lm * w.x;
      a1 += lm * w.y;
    }
    ws[WS_LATP + b * FCH + c0] = a0 + scb0[c0];
    ws[WS_LATP + b * FCH + c0 + 1] = a1 + scb0[c0 + 1];
  } else if (blk < 790) {
    int id = (blk - 534) * 256 + t;   // 65536
    int e = id & 7, lane = (id >> 3) & 63, tile = id >> 9;  // tile = colTile*4 + kTile
    int colTile = tile >> 2, kTile = tile & 3;
    int col = colTile * 16 + (lane & 15);
    int k = kTile * 32 + (lane >> 4) * 8 + e;
    w0t[id] = f2bf(scW0[k * FCH + col]);
  } else {
    int id = (blk - 790) * 256 + t;   // 262144
    int e = id & 7, lane = (id >> 3) & 63, tile = id >> 9;  // tile = colTile*16 + kTile
    int colTile = tile >> 4, kTile = tile & 15;
    int col = colTile * 16 + (lane & 15);
    int k = kTile * 32 + (lane >> 4) * 8 + e;
    w1t[id] = f2bf(scW1[k * FCH + col]);
  }
}

// ---------------- per-node geometry ----------------
__global__ void k_node(const float* frac, const float* noise, const int* batch, float* ws) {
  int n = blockIdx.x * blockDim.x + threadIdx.x;
  if (n >= Nn) return;
  int b = batch[n];
  float L[9], Li[9];
#pragma unroll
  for (int i = 0; i < 9; ++i) { L[i] = ws[WS_L + b * 9 + i]; Li[i] = ws[WS_LI + b * 9 + i]; }
  float f0 = frac[n * 3], f1 = frac[n * 3 + 1], f2 = frac[n * 3 + 2];
  float cg[3], p0[3], fp[3], pe[3], fg[3], fd[3];
#pragma unroll
  for (int j = 0; j < 3; ++j) cg[j] = f0 * L[j] + f1 * L[3 + j] + f2 * L[6 + j];
  float sig = ws[WS_SIG + b];
#pragma unroll
  for (int j = 0; j < 3; ++j) p0[j] = cg[j] + sig * noise[n * 3 + j];
#pragma unroll
  for (int j = 0; j < 3; ++j) {
    float v = p0[0] * Li[j] + p0[1] * Li[3 + j] + p0[2] * Li[6 + j];
    fp[j] = v - floorf(v);
  }
#pragma unroll
  for (int j = 0; j < 3; ++j) pe[j] = fp[0] * L[j] + fp[1] * L[3 + j] + fp[2] * L[6 + j];
#pragma unroll
  for (int j = 0; j < 3; ++j) fg[j] = cg[0] * Li[j] + cg[1] * Li[3 + j] + cg[2] * Li[6 + j];
#pragma unroll
  for (int j = 0; j < 3; ++j) { float d = fg[j] - fp[j]; fd[j] = d - rintf(d); }
#pragma unroll
  for (int j = 0; j < 3; ++j) {
    ws[WS_PERT + n * 3 + j] = pe[j];
    ws[WS_ALIGN + n * 3 + j] = pe[j] + fd[0] * L[j] + fd[1] * L[3 + j] + fd[2] * L[6 + j];
  }
}

// ---------------- the big fused MFMA edge kernel ----------------
// Tile: 64 edges x 512 cols. 8 waves; wave w owns cols [w*64, w*64+64)
// (4 col-tiles) across all 4 edge m-tiles.
// mfma_f32_16x16x32_bf16: A-frag lane l holds A[l&15][8*(l>>4)+e];
// B-frag lane l holds B[8*(l>>4)+e][l&15]; D: col=l&15, row=(l>>4)*4+r.
__global__ __launch_bounds__(512, 2) void k_edge(
    const int* ei, const int* toj, const int* batch, const int* atype,
    const unsigned short* w0t, const unsigned short* w1t,
    const float* scb1, const float* scW2, const float* scb2, float* ws) {
  __shared__ unsigned short s_ef[TE * HID];   // 16 KB, XOR-swizzled rows (256B)
  __shared__ unsigned short s_hh[TE * FCH];   // 64 KB, XOR-swizzled rows (1024B)
  __shared__ float s_latp[FCH];               // 2 KB
  __shared__ float s_rbf[TE][NRBF];           // 4 KB
  __shared__ float s_dvec[TE][3];
  __shared__ float s_dist[TE], s_gtd[TE];
  __shared__ int s_tj[TE], s_ti[TE];
  __shared__ float s_wsum[8][TE];             // 2 KB

  char* s_ef_b = (char*)s_ef;
  char* s_hh_b = (char*)s_hh;
  const int t = threadIdx.x;
  const int e0 = blockIdx.x * TE;

  // ---- Phase A: latp staging (tile lies within one graph) + per-edge geometry
  int b0 = batch[ei[e0]];
  if (t < 128) {
    ((float4*)s_latp)[t] = ((const float4*)(ws + WS_LATP + b0 * FCH))[t];
  }
  if (t < TE) {
    int e = e0 + t;
    int jn = ei[e], iN = ei[Ee + e];
    int b = batch[jn];
    float tx = (float)toj[e * 3], ty = (float)toj[e * 3 + 1], tz = (float)toj[e * 3 + 2];
    const float* L = ws + WS_L + b * 9;
    float dv[3], gv[3];
#pragma unroll
    for (int j = 0; j < 3; ++j) {
      float off = tx * L[j] + ty * L[3 + j] + tz * L[6 + j];
      dv[j] = ws[WS_PERT + iN * 3 + j] - ws[WS_PERT + jn * 3 + j] - off;
      gv[j] = ws[WS_ALIGN + iN * 3 + j] - ws[WS_ALIGN + jn * 3 + j] - off;
    }
    float dist = sqrtf(dv[0] * dv[0] + dv[1] * dv[1] + dv[2] * dv[2]);
    float gtd = sqrtf(gv[0] * gv[0] + gv[1] * gv[1] + gv[2] * gv[2]);
#pragma unroll
    for (int j = 0; j < 3; ++j) s_dvec[t][j] = dv[j];
    s_dist[t] = dist;
    s_gtd[t] = gtd;
    s_tj[t] = atype[jn]; s_ti[t] = atype[iN];
    const float step = 7.0f / 15.0f;
#pragma unroll
    for (int k = 0; k < NRBF; ++k) {
      float d = dist - (float)k * step;
      s_rbf[t][k] = __expf(-10.f * d * d);
    }
  }
  __syncthreads();

  // ---- Phase B: ef = silu(hb[tj]+hb[ti]+rbf@rbfW2+cvec) -> bf16 LDS (swizzled)
  {
    int e = t >> 3;              // 0..63
    int c0 = (t & 7) * 16;       // 16 cols per thread
    int tj = s_tj[e], ti = s_ti[e];
    float4 z4[4];
#pragma unroll
    for (int q = 0; q < 4; ++q) {
      float4 a = *(const float4*)(ws + WS_HB + tj * HID + c0 + q * 4);
      float4 bq = *(const float4*)(ws + WS_HB + ti * HID + c0 + q * 4);
      float4 cv = *(const float4*)(ws + WS_CVEC + c0 + q * 4);
      z4[q].x = a.x + bq.x + cv.x; z4[q].y = a.y + bq.y + cv.y;
      z4[q].z = a.z + bq.z + cv.z; z4[q].w = a.w + bq.w + cv.w;
    }
#pragma unroll
    for (int k = 0; k < NRBF; ++k) {
      float rbk = s_rbf[e][k];
#pragma unroll
      for (int q = 0; q < 4; ++q) {
        float4 wv4 = *(const float4*)(ws + WS_RBFW2 + k * HID + c0 + q * 4);
        z4[q].x += rbk * wv4.x; z4[q].y += rbk * wv4.y;
        z4[q].z += rbk * wv4.z; z4[q].w += rbk * wv4.w;
      }
    }
    u16x8 o0, o1;
#pragma unroll
    for (int q = 0; q < 4; ++q) {
      float zz[4] = {z4[q].x, z4[q].y, z4[q].z, z4[q].w};
#pragma unroll
      for (int j = 0; j < 4; ++j) {
        float z = zz[j];
        float sv = z / (1.f + __expf(-z));
        unsigned short us = f2bf(sv);
        if (q < 2) o0[q * 4 + j] = us; else o1[(q - 2) * 4 + j] = us;
      }
    }
    int base = e * 256 + c0 * 2;
    int sw = (e & 7) << 4;
    *(u16x8*)(s_ef_b + ((base) ^ sw)) = o0;
    *(u16x8*)(s_ef_b + ((base + 16) ^ sw)) = o1;
  }
  __syncthreads();

  const int lane = t & 63;
  const int wv = t >> 6;        // 0..7
  const int lr = lane & 15;     // col (D) / row (A) index
  const int lq = lane >> 4;     // k-quadrant

  // ---- Phase C: GEMM1  hh = relu(ef @ W0a + latp), bf16 -> LDS (swizzled)
  {
    f32x4 acc[4][4];
#pragma unroll
    for (int m = 0; m < 4; ++m)
#pragma unroll
      for (int n = 0; n < 4; ++n) acc[m][n] = (f32x4){0.f, 0.f, 0.f, 0.f};
    const unsigned short* w0l = w0t + lane * 8;
    // preload ALL W0 fragments for this wave (16 frags)
    bf16x8 bw[4][4];
#pragma unroll
    for (int kt = 0; kt < 4; ++kt)
#pragma unroll
      for (int n = 0; n < 4; ++n)
        bw[kt][n] = *(const bf16x8*)(w0l + (size_t)((wv * 4 + n) * 4 + kt) * 512);
#pragma unroll
    for (int kt = 0; kt < 4; ++kt) {
      bf16x8 a[4];
#pragma unroll
      for (int m = 0; m < 4; ++m) {
        int row = m * 16 + lr;
        int off = (row * 256 + (kt * 32 + lq * 8) * 2) ^ ((row & 7) << 4);
        a[m] = *(const bf16x8*)(s_ef_b + off);
      }
      __builtin_amdgcn_s_setprio(1);
#pragma unroll
      for (int n = 0; n < 4; ++n)
#pragma unroll
        for (int m = 0; m < 4; ++m)
          acc[m][n] = __builtin_amdgcn_mfma_f32_16x16x32_bf16(a[m], bw[kt][n], acc[m][n], 0, 0, 0);
      __builtin_amdgcn_s_setprio(0);
    }
#pragma unroll
    for (int m = 0; m < 4; ++m)
#pragma unroll
      for (int n = 0; n < 4; ++n) {
        int col = wv * 64 + n * 16 + lr;
        float lp = s_latp[col];
        f32x4 v = acc[m][n];
#pragma unroll
        for (int r = 0; r < 4; ++r) {
          int row = m * 16 + lq * 4 + r;
          float h = fmaxf(v[r] + lp, 0.f);
          int off = (row * 1024 + col * 2) ^ ((row & 7) << 4);
          *(unsigned short*)(s_hh_b + off) = f2bf(h);
        }
      }
  }
  __syncthreads();

  // ---- Phase D: GEMM2 with static ring-buffer pipeline (B 2-deep, A 1-deep)
  {
    f32x4 acc[4][4];
#pragma unroll
    for (int m = 0; m < 4; ++m)
#pragma unroll
      for (int n = 0; n < 4; ++n) acc[m][n] = (f32x4){0.f, 0.f, 0.f, 0.f};
    const unsigned short* w1l = w1t + lane * 8;

    bf16x8 bR[3][4];   // ring: holds kt, kt+1, kt+2
    bf16x8 aR[2][4];   // ring: holds kt, kt+1

    // prologue: B for kt=0,1; A for kt=0
#pragma unroll
    for (int n = 0; n < 4; ++n) {
      bR[0][n] = *(const bf16x8*)(w1l + (size_t)((wv * 4 + n) * 16 + 0) * 512);
      bR[1][n] = *(const bf16x8*)(w1l + (size_t)((wv * 4 + n) * 16 + 1) * 512);
    }
#pragma unroll
    for (int m = 0; m < 4; ++m) {
      int row = m * 16 + lr;
      int off = (row * 1024 + (lq * 8) * 2) ^ ((row & 7) << 4);
      aR[0][m] = *(const bf16x8*)(s_hh_b + off);
    }

#pragma unroll
    for (int kt = 0; kt < 16; ++kt) {
      // issue B loads for kt+2 (static index after unroll)
      if (kt + 2 < 16) {
#pragma unroll
        for (int n = 0; n < 4; ++n)
          bR[(kt + 2) % 3][n] =
              *(const bf16x8*)(w1l + (size_t)((wv * 4 + n) * 16 + kt + 2) * 512);
      }
      // issue A ds_reads for kt+1
      if (kt + 1 < 16) {
#pragma unroll
        for (int m = 0; m < 4; ++m) {
          int row = m * 16 + lr;
          int off = (row * 1024 + ((kt + 1) * 32 + lq * 8) * 2) ^ ((row & 7) << 4);
          aR[(kt + 1) & 1][m] = *(const bf16x8*)(s_hh_b + off);
        }
      }
      __builtin_amdgcn_s_setprio(1);
#pragma unroll
      for (int n = 0; n < 4; ++n)
#pragma unroll
        for (int m = 0; m < 4; ++m)
          acc[m][n] = __builtin_amdgcn_mfma_f32_16x16x32_bf16(
              aR[kt & 1][m], bR[kt % 3][n], acc[m][n], 0, 0, 0);
      __builtin_amdgcn_s_setprio(0);
    }

    // hh1 = relu(acc + b1); p += hh1 * W2   (per lane: 4 cols x 16 rows)
    float p[4][4];
#pragma unroll
    for (int m = 0; m < 4; ++m)
#pragma unroll
      for (int r = 0; r < 4; ++r) p[m][r] = 0.f;
#pragma unroll
    for (int n = 0; n < 4; ++n) {
      int col = wv * 64 + n * 16 + lr;
      float b1v = scb1[col];
      float w2v = scW2[col];
#pragma unroll
      for (int m = 0; m < 4; ++m) {
        f32x4 v = acc[m][n];
#pragma unroll
        for (int r = 0; r < 4; ++r) p[m][r] += fmaxf(v[r] + b1v, 0.f) * w2v;
      }
    }
    // reduce over the 16 lanes sharing a row (lane bits 0..3)
#pragma unroll
    for (int m = 0; m < 4; ++m)
#pragma unroll
      for (int r = 0; r < 4; ++r) {
        float x = p[m][r];
        x += __shfl_xor(x, 1);
        x += __shfl_xor(x, 2);
        x += __shfl_xor(x, 4);
        x += __shfl_xor(x, 8);
        p[m][r] = x;
      }
    if (lr == 0) {
#pragma unroll
      for (int m = 0; m < 4; ++m)
#pragma unroll
        for (int r = 0; r < 4; ++r) s_wsum[wv][m * 16 + lq * 4 + r] = p[m][r];
    }
  }
  __syncthreads();

  // ---- Phase E: segment-mean scatter (threads 0..63)
  if (t < TE) {
    int e = e0 + t;
    float score = scb2[0];
#pragma unroll
    for (int w = 0; w < 8; ++w) score += s_wsum[w][t];
    int jn = ei[e], iN = ei[Ee + e];
    int s = e;
    while (s > 0 && ei[s - 1] == jn && ei[Ee + s - 1] == iN) --s;
    int en = e;
    while (en + 1 < Ee && ei[en + 1] == jn && ei[Ee + en + 1] == iN) ++en;
    float invc = 1.f / (float)(en - s + 1);
    float dist = s_dist[t];
    float denom = dist + 1e-8f;
    float gts = s_gtd[t] - dist;
#pragma unroll
    for (int j = 0; j < 3; ++j) {
      float dir = s_dvec[t][j] / denom;
      atomicAdd(&ws[WS_SN + iN * 3 + j], score * dir * invc);
      atomicAdd(&ws[WS_GN + iN * 3 + j], gts * dir * invc);
    }
  }
}

// ---------------- per-node: loss terms, preds, center sums ----------------
__global__ void k_node2(const int* batch, float* ws) {
  int n = blockIdx.x * blockDim.x + threadIdx.x;
  if (n >= Nn) return;
  int b = batch[n];
  float sig = ws[WS_SIG + b];
#pragma unroll
  for (int j = 0; j < 3; ++j) {
    float s = ws[WS_SN + n * 3 + j], g = ws[WS_GN + n * 3 + j];
    float d = s - g / sig;
    atomicAdd(&ws[WS_BSUM + b * 3 + j], d * d);
    float pr = ws[WS_PERT + n * 3 + j] + s / sig;
    ws[WS_PREDS + n * 3 + j] = pr;
    atomicAdd(&ws[WS_CENTER + b * 3 + j], pr);
  }
}

// ---------------- per-node: global min/max of dc ----------------
__global__ void k_minmax(const int* batch, const int* num_atoms, float* ws) {
  int n = blockIdx.x * blockDim.x + threadIdx.x;
  int lane = threadIdx.x & 63, wid = threadIdx.x >> 6;
  float mx[3], mn[3];
  if (n < Nn) {
    int b = batch[n];
    float na = (float)num_atoms[b];
#pragma unroll
    for (int j = 0; j < 3; ++j) {
      float v = ws[WS_PREDS + n * 3 + j] - ws[WS_CENTER + b * 3 + j] / na;
      mx[j] = v; mn[j] = v;
    }
  } else {
#pragma unroll
    for (int j = 0; j < 3; ++j) { mx[j] = -3.0e38f; mn[j] = 3.0e38f; }
  }
#pragma unroll
  for (int off = 32; off >= 1; off >>= 1) {
#pragma unroll
    for (int j = 0; j < 3; ++j) {
      mx[j] = fmaxf(mx[j], __shfl_xor(mx[j], off));
      mn[j] = fminf(mn[j], __shfl_xor(mn[j], off));
    }
  }
  __shared__ float smx[4][3], smn[4][3];
  if (lane == 0) {
#pragma unroll
    for (int j = 0; j < 3; ++j) { smx[wid][j] = mx[j]; smn[wid][j] = mn[j]; }
  }
  __syncthreads();
  if (threadIdx.x == 0) {
#pragma unroll
    for (int j = 0; j < 3; ++j) {
      float M = fmaxf(fmaxf(smx[0][j], smx[1][j]), fmaxf(smx[2][j], smx[3][j]));
      float m = fminf(fminf(smn[0][j], smn[1][j]), fminf(smn[2][j], smn[3][j]));
      atomicMaxFloat(&ws[WS_MINMAX + j], M);
      atomicMinFloat(&ws[WS_MINMAX + 3 + j], m);
    }
  }
}

// ---------------- finalize (parallel over batches) ----------------
__global__ void k_final(const int* num_atoms, const float* ws, float* out) {
  int t = threadIdx.x;  // 128 threads
  float loss = 0.f;
  if (t < Bb) {
    float na = (float)num_atoms[t];
    loss = (ws[WS_BSUM + t * 3] + ws[WS_BSUM + t * 3 + 1] + ws[WS_BSUM + t * 3 + 2]) / na;
  }
#pragma unroll
  for (int off = 32; off >= 1; off >>= 1) loss += __shfl_xor(loss, off);
  __shared__ float s2[2];
  if ((t & 63) == 0) s2[t >> 6] = loss;
  __syncthreads();
  if (t == 0) {
    float L = (s2[0] + s2[1]) / (3.0f * (float)Bb);
    float pbs = fabsf(ws[WS_MINMAX + 0] + ws[WS_MINMAX + 3]) +
                fabsf(ws[WS_MINMAX + 1] + ws[WS_MINMAX + 4]) +
                fabsf(ws[WS_MINMAX + 2] + ws[WS_MINMAX + 5]);
    out[0] = L;
    out[1] = pbs;
  }
}

extern "C" void kernel_launch(void* const* d_in, const int* in_sizes, int n_in,
                              void* d_out, int out_size, void* d_ws, size_t ws_size,
                              hipStream_t stream) {
  const float* latents = (const float*)d_in[0];
  const float* gtf     = (const float*)d_in[1];
  const float* lengths = (const float*)d_in[2];
  const float* angles  = (const float*)d_in[3];
  const float* noise   = (const float*)d_in[4];
  const float* sigmas  = (const float*)d_in[5];
  const float* aemb    = (const float*)d_in[6];
  const float* rbfW    = (const float*)d_in[7];
  const float* rbfb    = (const float*)d_in[8];
  const float* bbW     = (const float*)d_in[9];
  const float* bbb     = (const float*)d_in[10];
  const float* scW0    = (const float*)d_in[11];
  const float* scb0    = (const float*)d_in[12];
  const float* scW1    = (const float*)d_in[13];
  const float* scb1    = (const float*)d_in[14];
  const float* scW2    = (const float*)d_in[15];
  const float* scb2    = (const float*)d_in[16];
  const int* num_atoms = (const int*)d_in[17];
  const int* atype     = (const int*)d_in[18];
  const int* batch     = (const int*)d_in[19];
  const int* ei        = (const int*)d_in[20];
  const int* toj       = (const int*)d_in[21];
  const int* tsteps    = (const int*)d_in[22];
  float* ws = (float*)d_ws;
  float* out = (float*)d_out;
  unsigned short* w0t = (unsigned short*)(ws + WS_W0T_F);
  unsigned short* w1t = (unsigned short*)(ws + WS_W1T_F);

  hipLaunchKernelGGL(k_pre, dim3(1814), dim3(256), 0, stream,
                     lengths, angles, sigmas, tsteps, aemb, bbW, rbfW, rbfb, bbb,
                     latents, scW0, scb0, scW1, w0t, w1t, ws);
  hipLaunchKernelGGL(k_node, dim3(50), dim3(256), 0, stream, gtf, noise, batch, ws);
  hipLaunchKernelGGL(k_edge, dim3(Ee / TE), dim3(512), 0, stream,
                     ei, toj, batch, atype, w0t, w1t, scb1, scW2, scb2, ws);
  hipLaunchKernelGGL(k_node2, dim3(50), dim3(256), 0, stream, batch, ws);
  hipLaunchKernelGGL(k_minmax, dim3(50), dim3(256), 0, stream, batch, num_atoms, ws);
  hipLaunchKernelGGL(k_final, dim3(1), dim3(128), 0, stream, num_atoms, ws, out);
}

// Round 7
// 383.253 us; speedup vs baseline: 7.3146x; 1.3199x over previous
//
#include <hip/hip_runtime.h>
#include <hip/hip_bf16.h>

// ---------------- problem constants ----------------
namespace {
constexpr int Bb = 128, Nn = 12800, Ee = 262144;
constexpr int LAT = 256, HID = 128, FCH = 512, NRBF = 16;
constexpr int TE = 32; // edges per block in edge kernel (divides 2048 = edges/graph)

// workspace offsets (floats)
constexpr int WS_L      = 0;        // B*9
constexpr int WS_LI     = 1152;     // B*9
constexpr int WS_SIG    = 2304;     // B
constexpr int WS_RBFW2  = 2432;     // 16*128
constexpr int WS_CVEC   = 4480;     // 128
constexpr int WS_HB     = 4608;     // 100*128
constexpr int WS_LATP   = 17408;    // B*512
constexpr int WS_PERT   = 82944;    // N*3
constexpr int WS_ALIGN  = 121344;   // N*3
constexpr int WS_SN     = 159744;   // N*3 (atomic)
constexpr int WS_GN     = 198144;   // N*3 (atomic)
constexpr int WS_PREDS  = 236544;   // N*3
constexpr int WS_BSUM   = 274944;   // B*3 (atomic)
constexpr int WS_CENTER = 275328;   // B*3 (atomic)
constexpr int WS_MINMAX = 275712;   // 6   (max x3, min x3)
// bf16 fragment-tiled weights (stored as ushort), float-index base:
constexpr int WS_W0T_F  = 276000;   // ushort[512*128]  (= 32768 floats)
constexpr int WS_W1T_F  = 308768;   // ushort[512*512]  (= 131072 floats)
}

typedef short bf16x8 __attribute__((ext_vector_type(8)));
typedef unsigned short u16x8 __attribute__((ext_vector_type(8)));
typedef float f32x4 __attribute__((ext_vector_type(4)));

static __device__ __forceinline__ unsigned short f2bf(float f) {
  unsigned int u = __float_as_uint(f);
  unsigned int r = (u + 0x7fffu + ((u >> 16) & 1u)) >> 16;
  return (unsigned short)r;
}

static __device__ __forceinline__ void atomicMaxFloat(float* addr, float val) {
  int* ai = reinterpret_cast<int*>(addr);
  int old = *ai;
  while (__int_as_float(old) < val) {
    int assumed = old;
    old = atomicCAS(ai, assumed, __float_as_int(val));
    if (old == assumed) break;
  }
}
static __device__ __forceinline__ void atomicMinFloat(float* addr, float val) {
  int* ai = reinterpret_cast<int*>(addr);
  int old = *ai;
  while (__int_as_float(old) > val) {
    int assumed = old;
    old = atomicCAS(ai, assumed, __float_as_int(val));
    if (old == assumed) break;
  }
}

// ---------------- fused prologue: all mutually-independent prep work ----------------
__global__ __launch_bounds__(256) void k_pre(
    const float* lengths, const float* angles, const float* sigmas, const int* tsteps,
    const float* aemb, const float* bbW, const float* rbfW, const float* rbfb,
    const float* bbb, const float* latents, const float* scW0, const float* scb0,
    const float* scW1, unsigned short* w0t, unsigned short* w1t, float* ws) {
  const int blk = blockIdx.x, t = threadIdx.x;
  if (blk < 304) {
    int gid = blk * 256 + t;
    if (gid < 2 * Nn * 3) ws[WS_SN + gid] = 0.f;
    else if (gid < 2 * Nn * 3 + 2 * Bb * 3) ws[WS_BSUM + (gid - 2 * Nn * 3)] = 0.f;
    else if (gid < 2 * Nn * 3 + 2 * Bb * 3 + 3) ws[WS_MINMAX + (gid - 2 * Nn * 3 - 2 * Bb * 3)] = -3.0e38f;
    else if (gid < 2 * Nn * 3 + 2 * Bb * 3 + 6) ws[WS_MINMAX + (gid - 2 * Nn * 3 - 2 * Bb * 3)] = 3.0e38f;
  } else if (blk == 304) {
    int b = t;
    if (b >= Bb) return;
    float a = lengths[b * 3 + 0], bl = lengths[b * 3 + 1], c = lengths[b * 3 + 2];
    const float d2r = 0.017453292519943295f;
    float al = angles[b * 3 + 0] * d2r, be = angles[b * 3 + 1] * d2r, ga = angles[b * 3 + 2] * d2r;
    float ca = cosf(al), cb = cosf(be), cg = cosf(ga), sa = sinf(al), sb = sinf(be);
    float val = (ca * cb - cg) / (sa * sb);
    val = fminf(1.f, fmaxf(-1.f, val));
    float gs = acosf(val);
    float L[3][3];
    L[0][0] = a * sb;              L[0][1] = 0.f;                L[0][2] = a * cb;
    L[1][0] = -bl * sa * cosf(gs); L[1][1] = bl * sa * sinf(gs); L[1][2] = bl * ca;
    L[2][0] = 0.f;                 L[2][1] = 0.f;                L[2][2] = c;
    float det = L[0][0] * (L[1][1] * L[2][2] - L[1][2] * L[2][1])
              - L[0][1] * (L[1][0] * L[2][2] - L[1][2] * L[2][0])
              + L[0][2] * (L[1][0] * L[2][1] - L[1][1] * L[2][0]);
    float id = 1.f / det;
    float inv[3][3];
    inv[0][0] =  (L[1][1]*L[2][2] - L[1][2]*L[2][1]) * id;
    inv[0][1] = -(L[0][1]*L[2][2] - L[0][2]*L[2][1]) * id;
    inv[0][2] =  (L[0][1]*L[1][2] - L[0][2]*L[1][1]) * id;
    inv[1][0] = -(L[1][0]*L[2][2] - L[1][2]*L[2][0]) * id;
    inv[1][1] =  (L[0][0]*L[2][2] - L[0][2]*L[2][0]) * id;
    inv[1][2] = -(L[0][0]*L[1][2] - L[0][2]*L[1][0]) * id;
    inv[2][0] =  (L[1][0]*L[2][1] - L[1][1]*L[2][0]) * id;
    inv[2][1] = -(L[0][0]*L[2][1] - L[0][1]*L[2][0]) * id;
    inv[2][2] =  (L[0][0]*L[1][1] - L[0][1]*L[1][0]) * id;
    for (int i = 0; i < 3; ++i)
      for (int j = 0; j < 3; ++j) {
        ws[WS_L + b * 9 + i * 3 + j] = L[i][j];
        ws[WS_LI + b * 9 + i * 3 + j] = inv[i][j];
      }
    ws[WS_SIG + b] = sigmas[tsteps[b]];
  } else if (blk < 405) {
    int tile = blk - 305;
    if (t < HID) {
      float acc = 0.f;
      for (int k = 0; k < HID; ++k) acc += aemb[tile * HID + k] * bbW[k * HID + t];
      ws[WS_HB + tile * HID + t] = acc;
    }
  } else if (blk == 405) {
    if (t < HID) {
      float accs[NRBF];
#pragma unroll
      for (int k = 0; k < NRBF; ++k) accs[k] = 0.f;
      float accb = 0.f;
      for (int m = 0; m < HID; ++m) {
        float w = bbW[m * HID + t];
#pragma unroll
        for (int k = 0; k < NRBF; ++k) accs[k] += rbfW[k * HID + m] * w;
        accb += rbfb[m] * w;
      }
#pragma unroll
      for (int k = 0; k < NRBF; ++k) ws[WS_RBFW2 + k * HID + t] = accs[k];
      ws[WS_CVEC + t] = accb + bbb[t];
    }
  } else if (blk < 534) {
    int b = blk - 406;
    __shared__ float lat[LAT];
    lat[t] = latents[b * LAT + t];
    __syncthreads();
    int c0 = 2 * t;
    float a0 = 0.f, a1 = 0.f;
    for (int m = 0; m < LAT; ++m) {
      float2 w = *reinterpret_cast<const float2*>(scW0 + (HID + m) * FCH + c0);
      float lm = lat[m];
      a0 += lm * w.x;
      a1 += lm * w.y;
    }
    ws[WS_LATP + b * FCH + c0] = a0 + scb0[c0];
    ws[WS_LATP + b * FCH + c0 + 1] = a1 + scb0[c0 + 1];
  } else if (blk < 790) {
    int id = (blk - 534) * 256 + t;   // 65536
    int e = id & 7, lane = (id >> 3) & 63, tile = id >> 9;  // tile = colTile*4 + kTile
    int colTile = tile >> 2, kTile = tile & 3;
    int col = colTile * 16 + (lane & 15);
    int k = kTile * 32 + (lane >> 4) * 8 + e;
    w0t[id] = f2bf(scW0[k * FCH + col]);
  } else {
    int id = (blk - 790) * 256 + t;   // 262144
    int e = id & 7, lane = (id >> 3) & 63, tile = id >> 9;  // tile = colTile*16 + kTile
    int colTile = tile >> 4, kTile = tile & 15;
    int col = colTile * 16 + (lane & 15);
    int k = kTile * 32 + (lane >> 4) * 8 + e;
    w1t[id] = f2bf(scW1[k * FCH + col]);
  }
}

// ---------------- per-node geometry ----------------
__global__ void k_node(const float* frac, const float* noise, const int* batch, float* ws) {
  int n = blockIdx.x * blockDim.x + threadIdx.x;
  if (n >= Nn) return;
  int b = batch[n];
  float L[9], Li[9];
#pragma unroll
  for (int i = 0; i < 9; ++i) { L[i] = ws[WS_L + b * 9 + i]; Li[i] = ws[WS_LI + b * 9 + i]; }
  float f0 = frac[n * 3], f1 = frac[n * 3 + 1], f2 = frac[n * 3 + 2];
  float cg[3], p0[3], fp[3], pe[3], fg[3], fd[3];
#pragma unroll
  for (int j = 0; j < 3; ++j) cg[j] = f0 * L[j] + f1 * L[3 + j] + f2 * L[6 + j];
  float sig = ws[WS_SIG + b];
#pragma unroll
  for (int j = 0; j < 3; ++j) p0[j] = cg[j] + sig * noise[n * 3 + j];
#pragma unroll
  for (int j = 0; j < 3; ++j) {
    float v = p0[0] * Li[j] + p0[1] * Li[3 + j] + p0[2] * Li[6 + j];
    fp[j] = v - floorf(v);
  }
#pragma unroll
  for (int j = 0; j < 3; ++j) pe[j] = fp[0] * L[j] + fp[1] * L[3 + j] + fp[2] * L[6 + j];
#pragma unroll
  for (int j = 0; j < 3; ++j) fg[j] = cg[0] * Li[j] + cg[1] * Li[3 + j] + cg[2] * Li[6 + j];
#pragma unroll
  for (int j = 0; j < 3; ++j) { float d = fg[j] - fp[j]; fd[j] = d - rintf(d); }
#pragma unroll
  for (int j = 0; j < 3; ++j) {
    ws[WS_PERT + n * 3 + j] = pe[j];
    ws[WS_ALIGN + n * 3 + j] = pe[j] + fd[0] * L[j] + fd[1] * L[3 + j] + fd[2] * L[6 + j];
  }
}

// ---------------- the big fused MFMA edge kernel ----------------
// Tile: 32 edges x 512 cols. 4 waves; wave wv owns cols [wv*128, wv*128+128).
// LDS budget ~33.7 KB -> 4 blocks/CU (16 waves/CU, 4 waves/SIMD).
// s_ef (8KB, swizzled [32][256B]) ALIASES s_hh bytes 0..8191;
// rbfW2 (8KB) staged at s_hh+8192; cvec (512B) at s_hh+16384 — all dead
// before the GEMM1 epilogue overwrites s_hh (barrier-enforced).
// mfma_f32_16x16x32_bf16: A-frag lane l holds A[l&15][8*(l>>4)+e];
// B-frag lane l holds B[8*(l>>4)+e][l&15]; D: col=l&15, row=(l>>4)*4+r.
__global__ __launch_bounds__(256, 4) void k_edge(
    const int* ei, const int* toj, const int* batch, const int* atype,
    const unsigned short* w0t, const unsigned short* w1t,
    const float* scb1, const float* scW2, const float* scb2, float* ws) {
  __shared__ unsigned short s_hh[TE * FCH];   // 32 KB, XOR-swizzled rows (1024B)
  __shared__ float s_dvec[TE][3];
  __shared__ float s_dist[TE], s_gtd[TE];
  __shared__ int s_tj[TE], s_ti[TE];
  __shared__ float s_wsum[4][TE];

  char* s_hh_b = (char*)s_hh;
  char* s_ef_b = s_hh_b;                          // alias: [32][256B] swizzled
  float* s_rbfw2 = (float*)(s_hh_b + 8192);       // [16][128] f32 (8 KB)
  float* s_cvec  = (float*)(s_hh_b + 16384);      // [128] f32 (512 B)

  const int t = threadIdx.x;
  const int e0 = blockIdx.x * TE;
  const int b0 = batch[ei[e0]];

  // ---- Phase A: stage rbfW2+cvec to LDS; per-edge geometry (t<32)
  {
    const float4* src = (const float4*)(ws + WS_RBFW2);  // 2048 floats = 512 float4
    float4* dst = (float4*)s_rbfw2;
#pragma unroll
    for (int q = 0; q < 2; ++q) dst[q * 256 + t] = src[q * 256 + t];
    if (t < 32) ((float4*)s_cvec)[t] = ((const float4*)(ws + WS_CVEC))[t];
  }
  if (t < TE) {
    int e = e0 + t;
    int jn = ei[e], iN = ei[Ee + e];
    int b = batch[jn];
    float tx = (float)toj[e * 3], ty = (float)toj[e * 3 + 1], tz = (float)toj[e * 3 + 2];
    const float* L = ws + WS_L + b * 9;
    float dv[3], gv[3];
#pragma unroll
    for (int j = 0; j < 3; ++j) {
      float off = tx * L[j] + ty * L[3 + j] + tz * L[6 + j];
      dv[j] = ws[WS_PERT + iN * 3 + j] - ws[WS_PERT + jn * 3 + j] - off;
      gv[j] = ws[WS_ALIGN + iN * 3 + j] - ws[WS_ALIGN + jn * 3 + j] - off;
    }
    float dist = sqrtf(dv[0] * dv[0] + dv[1] * dv[1] + dv[2] * dv[2]);
    float gtd = sqrtf(gv[0] * gv[0] + gv[1] * gv[1] + gv[2] * gv[2]);
#pragma unroll
    for (int j = 0; j < 3; ++j) s_dvec[t][j] = dv[j];
    s_dist[t] = dist;
    s_gtd[t] = gtd;
    s_tj[t] = atype[jn]; s_ti[t] = atype[iN];
  }
  __syncthreads();

  // ---- Phase B: ef = silu(hb[tj]+hb[ti]+rbf@rbfW2+cvec) -> bf16 s_ef (swizzled)
  {
    int e = t >> 3;              // 0..31
    int c0 = (t & 7) * 16;       // 16 cols per thread
    int tj = s_tj[e], ti = s_ti[e];
    float dist = s_dist[e];
    const float step = 7.0f / 15.0f;
    float rb[NRBF];
#pragma unroll
    for (int k = 0; k < NRBF; ++k) {
      float d = dist - (float)k * step;
      rb[k] = __expf(-10.f * d * d);
    }
    float4 z4[4];
#pragma unroll
    for (int q = 0; q < 4; ++q) {
      float4 a = *(const float4*)(ws + WS_HB + tj * HID + c0 + q * 4);
      float4 bq = *(const float4*)(ws + WS_HB + ti * HID + c0 + q * 4);
      float4 cv = ((const float4*)s_cvec)[c0 / 4 + q];
      z4[q].x = a.x + bq.x + cv.x; z4[q].y = a.y + bq.y + cv.y;
      z4[q].z = a.z + bq.z + cv.z; z4[q].w = a.w + bq.w + cv.w;
    }
#pragma unroll
    for (int k = 0; k < NRBF; ++k) {
      float rbk = rb[k];
#pragma unroll
      for (int q = 0; q < 4; ++q) {
        float4 wv4 = ((const float4*)s_rbfw2)[k * 32 + c0 / 4 + q];
        z4[q].x += rbk * wv4.x; z4[q].y += rbk * wv4.y;
        z4[q].z += rbk * wv4.z; z4[q].w += rbk * wv4.w;
      }
    }
    u16x8 o0, o1;
#pragma unroll
    for (int q = 0; q < 4; ++q) {
      float zz[4] = {z4[q].x, z4[q].y, z4[q].z, z4[q].w};
#pragma unroll
      for (int j = 0; j < 4; ++j) {
        float z = zz[j];
        float sv = z / (1.f + __expf(-z));
        unsigned short us = f2bf(sv);
        if (q < 2) o0[q * 4 + j] = us; else o1[(q - 2) * 4 + j] = us;
      }
    }
    __syncthreads();   // (conservative) all LDS reads done before s_ef writes
    int base = e * 256 + c0 * 2;
    int sw = (e & 7) << 4;
    *(u16x8*)(s_ef_b + ((base) ^ sw)) = o0;
    *(u16x8*)(s_ef_b + ((base + 16) ^ sw)) = o1;
  }
  __syncthreads();

  const int lane = t & 63;
  const int wv = t >> 6;        // 0..3
  const int c0w = wv * 128;
  const int lr = lane & 15;     // col (D) / row (A) index
  const int lq = lane >> 4;     // k-quadrant

  // ---- Phase C: GEMM1  hh = relu(ef @ W0a + latp), bf16 -> s_hh (swizzled)
  {
    f32x4 acc[2][8];
#pragma unroll
    for (int m = 0; m < 2; ++m)
#pragma unroll
      for (int n = 0; n < 8; ++n) acc[m][n] = (f32x4){0.f, 0.f, 0.f, 0.f};
    const unsigned short* w0base = w0t + (size_t)(wv * 8) * 4 * 512 + lane * 8;
#pragma unroll
    for (int kt = 0; kt < 4; ++kt) {
      bf16x8 a[2];
#pragma unroll
      for (int m = 0; m < 2; ++m) {
        int row = m * 16 + lr;
        int off = (row * 256 + (kt * 32 + lq * 8) * 2) ^ ((row & 7) << 4);
        a[m] = *(const bf16x8*)(s_ef_b + off);
      }
      __builtin_amdgcn_s_setprio(1);
#pragma unroll
      for (int n = 0; n < 8; ++n) {
        bf16x8 bfr = *(const bf16x8*)(w0base + (n * 4 + kt) * 512);
        acc[0][n] = __builtin_amdgcn_mfma_f32_16x16x32_bf16(a[0], bfr, acc[0][n], 0, 0, 0);
        acc[1][n] = __builtin_amdgcn_mfma_f32_16x16x32_bf16(a[1], bfr, acc[1][n], 0, 0, 0);
      }
      __builtin_amdgcn_s_setprio(0);
    }
    __syncthreads();   // ALL s_ef reads complete before epilogue overwrites the alias
#pragma unroll
    for (int m = 0; m < 2; ++m)
#pragma unroll
      for (int n = 0; n < 8; ++n) {
        int col = c0w + n * 16 + lr;
        float lp = ws[WS_LATP + b0 * FCH + col];
        f32x4 v = acc[m][n];
#pragma unroll
        for (int r = 0; r < 4; ++r) {
          int row = m * 16 + lq * 4 + r;
          float h = fmaxf(v[r] + lp, 0.f);
          int off = (row * 1024 + col * 2) ^ ((row & 7) << 4);
          *(unsigned short*)(s_hh_b + off) = f2bf(h);
        }
      }
  }
  __syncthreads();

  // ---- Phase D: GEMM2 + fused score reduction
  {
    f32x4 acc[2][8];
#pragma unroll
    for (int m = 0; m < 2; ++m)
#pragma unroll
      for (int n = 0; n < 8; ++n) acc[m][n] = (f32x4){0.f, 0.f, 0.f, 0.f};
    const unsigned short* w1base = w1t + (size_t)(wv * 8) * 16 * 512 + lane * 8;
#pragma unroll 4
    for (int kt = 0; kt < 16; ++kt) {
      bf16x8 a[2];
#pragma unroll
      for (int m = 0; m < 2; ++m) {
        int row = m * 16 + lr;
        int off = (row * 1024 + (kt * 32 + lq * 8) * 2) ^ ((row & 7) << 4);
        a[m] = *(const bf16x8*)(s_hh_b + off);
      }
      __builtin_amdgcn_s_setprio(1);
#pragma unroll
      for (int n = 0; n < 8; ++n) {
        bf16x8 bfr = *(const bf16x8*)(w1base + (n * 16 + kt) * 512);
        acc[0][n] = __builtin_amdgcn_mfma_f32_16x16x32_bf16(a[0], bfr, acc[0][n], 0, 0, 0);
        acc[1][n] = __builtin_amdgcn_mfma_f32_16x16x32_bf16(a[1], bfr, acc[1][n], 0, 0, 0);
      }
      __builtin_amdgcn_s_setprio(0);
    }
    // hh1 = relu(acc + b1); p += hh1 * W2   (per lane: 8 cols x 8 rows)
    float p[2][4];
#pragma unroll
    for (int m = 0; m < 2; ++m)
#pragma unroll
      for (int r = 0; r < 4; ++r) p[m][r] = 0.f;
#pragma unroll
    for (int n = 0; n < 8; ++n) {
      int col = c0w + n * 16 + lr;
      float b1v = scb1[col];
      float w2v = scW2[col];
#pragma unroll
      for (int m = 0; m < 2; ++m) {
        f32x4 v = acc[m][n];
#pragma unroll
        for (int r = 0; r < 4; ++r) p[m][r] += fmaxf(v[r] + b1v, 0.f) * w2v;
      }
    }
    // reduce over the 16 lanes sharing a row (lane bits 0..3)
#pragma unroll
    for (int m = 0; m < 2; ++m)
#pragma unroll
      for (int r = 0; r < 4; ++r) {
        float x = p[m][r];
        x += __shfl_xor(x, 1);
        x += __shfl_xor(x, 2);
        x += __shfl_xor(x, 4);
        x += __shfl_xor(x, 8);
        p[m][r] = x;
      }
    if (lr == 0) {
#pragma unroll
      for (int m = 0; m < 2; ++m)
#pragma unroll
        for (int r = 0; r < 4; ++r) s_wsum[wv][m * 16 + lq * 4 + r] = p[m][r];
    }
  }
  __syncthreads();

  // ---- Phase E: segment-mean scatter (threads 0..31)
  if (t < TE) {
    int e = e0 + t;
    float score = scb2[0] + s_wsum[0][t] + s_wsum[1][t] + s_wsum[2][t] + s_wsum[3][t];
    int jn = ei[e], iN = ei[Ee + e];
    int s = e;
    while (s > 0 && ei[s - 1] == jn && ei[Ee + s - 1] == iN) --s;
    int en = e;
    while (en + 1 < Ee && ei[en + 1] == jn && ei[Ee + en + 1] == iN) ++en;
    float invc = 1.f / (float)(en - s + 1);
    float dist = s_dist[t];
    float denom = dist + 1e-8f;
    float gts = s_gtd[t] - dist;
#pragma unroll
    for (int j = 0; j < 3; ++j) {
      float dir = s_dvec[t][j] / denom;
      atomicAdd(&ws[WS_SN + iN * 3 + j], score * dir * invc);
      atomicAdd(&ws[WS_GN + iN * 3 + j], gts * dir * invc);
    }
  }
}

// ---------------- per-node: loss terms, preds, center sums ----------------
__global__ void k_node2(const int* batch, float* ws) {
  int n = blockIdx.x * blockDim.x + threadIdx.x;
  if (n >= Nn) return;
  int b = batch[n];
  float sig = ws[WS_SIG + b];
#pragma unroll
  for (int j = 0; j < 3; ++j) {
    float s = ws[WS_SN + n * 3 + j], g = ws[WS_GN + n * 3 + j];
    float d = s - g / sig;
    atomicAdd(&ws[WS_BSUM + b * 3 + j], d * d);
    float pr = ws[WS_PERT + n * 3 + j] + s / sig;
    ws[WS_PREDS + n * 3 + j] = pr;
    atomicAdd(&ws[WS_CENTER + b * 3 + j], pr);
  }
}

// ---------------- per-node: global min/max of dc ----------------
__global__ void k_minmax(const int* batch, const int* num_atoms, float* ws) {
  int n = blockIdx.x * blockDim.x + threadIdx.x;
  int lane = threadIdx.x & 63, wid = threadIdx.x >> 6;
  float mx[3], mn[3];
  if (n < Nn) {
    int b = batch[n];
    float na = (float)num_atoms[b];
#pragma unroll
    for (int j = 0; j < 3; ++j) {
      float v = ws[WS_PREDS + n * 3 + j] - ws[WS_CENTER + b * 3 + j] / na;
      mx[j] = v; mn[j] = v;
    }
  } else {
#pragma unroll
    for (int j = 0; j < 3; ++j) { mx[j] = -3.0e38f; mn[j] = 3.0e38f; }
  }
#pragma unroll
  for (int off = 32; off >= 1; off >>= 1) {
#pragma unroll
    for (int j = 0; j < 3; ++j) {
      mx[j] = fmaxf(mx[j], __shfl_xor(mx[j], off));
      mn[j] = fminf(mn[j], __shfl_xor(mn[j], off));
    }
  }
  __shared__ float smx[4][3], smn[4][3];
  if (lane == 0) {
#pragma unroll
    for (int j = 0; j < 3; ++j) { smx[wid][j] = mx[j]; smn[wid][j] = mn[j]; }
  }
  __syncthreads();
  if (threadIdx.x == 0) {
#pragma unroll
    for (int j = 0; j < 3; ++j) {
      float M = fmaxf(fmaxf(smx[0][j], smx[1][j]), fmaxf(smx[2][j], smx[3][j]));
      float m = fminf(fminf(smn[0][j], smn[1][j]), fminf(smn[2][j], smn[3][j]));
      atomicMaxFloat(&ws[WS_MINMAX + j], M);
      atomicMinFloat(&ws[WS_MINMAX + 3 + j], m);
    }
  }
}

// ---------------- finalize (parallel over batches) ----------------
__global__ void k_final(const int* num_atoms, const float* ws, float* out) {
  int t = threadIdx.x;  // 128 threads
  float loss = 0.f;
  if (t < Bb) {
    float na = (float)num_atoms[t];
    loss = (ws[WS_BSUM + t * 3] + ws[WS_BSUM + t * 3 + 1] + ws[WS_BSUM + t * 3 + 2]) / na;
  }
#pragma unroll
  for (int off = 32; off >= 1; off >>= 1) loss += __shfl_xor(loss, off);
  __shared__ float s2[2];
  if ((t & 63) == 0) s2[t >> 6] = loss;
  __syncthreads();
  if (t == 0) {
    float L = (s2[0] + s2[1]) / (3.0f * (float)Bb);
    float pbs = fabsf(ws[WS_MINMAX + 0] + ws[WS_MINMAX + 3]) +
                fabsf(ws[WS_MINMAX + 1] + ws[WS_MINMAX + 4]) +
                fabsf(ws[WS_MINMAX + 2] + ws[WS_MINMAX + 5]);
    out[0] = L;
    out[1] = pbs;
  }
}

extern "C" void kernel_launch(void* const* d_in, const int* in_sizes, int n_in,
                              void* d_out, int out_size, void* d_ws, size_t ws_size,
                              hipStream_t stream) {
  const float* latents = (const float*)d_in[0];
  const float* gtf     = (const float*)d_in[1];
  const float* lengths = (const float*)d_in[2];
  const float* angles  = (const float*)d_in[3];
  const float* noise   = (const float*)d_in[4];
  const float* sigmas  = (const float*)d_in[5];
  const float* aemb    = (const float*)d_in[6];
  const float* rbfW    = (const float*)d_in[7];
  const float* rbfb    = (const float*)d_in[8];
  const float* bbW     = (const float*)d_in[9];
  const float* bbb     = (const float*)d_in[10];
  const float* scW0    = (const float*)d_in[11];
  const float* scb0    = (const float*)d_in[12];
  const float* scW1    = (const float*)d_in[13];
  const float* scb1    = (const float*)d_in[14];
  const float* scW2    = (const float*)d_in[15];
  const float* scb2    = (const float*)d_in[16];
  const int* num_atoms = (const int*)d_in[17];
  const int* atype     = (const int*)d_in[18];
  const int* batch     = (const int*)d_in[19];
  const int* ei        = (const int*)d_in[20];
  const int* toj       = (const int*)d_in[21];
  const int* tsteps    = (const int*)d_in[22];
  float* ws = (float*)d_ws;
  float* out = (float*)d_out;
  unsigned short* w0t = (unsigned short*)(ws + WS_W0T_F);
  unsigned short* w1t = (unsigned short*)(ws + WS_W1T_F);

  hipLaunchKernelGGL(k_pre, dim3(1814), dim3(256), 0, stream,
                     lengths, angles, sigmas, tsteps, aemb, bbW, rbfW, rbfb, bbb,
                     latents, scW0, scb0, scW1, w0t, w1t, ws);
  hipLaunchKernelGGL(k_node, dim3(50), dim3(256), 0, stream, gtf, noise, batch, ws);
  hipLaunchKernelGGL(k_edge, dim3(Ee / TE), dim3(256), 0, stream,
                     ei, toj, batch, atype, w0t, w1t, scb1, scW2, scb2, ws);
  hipLaunchKernelGGL(k_node2, dim3(50), dim3(256), 0, stream, batch, ws);
  hipLaunchKernelGGL(k_minmax, dim3(50), dim3(256), 0, stream, batch, num_atoms, ws);
  hipLaunchKernelGGL(k_final, dim3(1), dim3(128), 0, stream, num_atoms, ws, out);
}